// Round 3
// baseline (1014.951 us; speedup 1.0000x reference)
//
#include <hip/hip_runtime.h>
#include <hip/hip_bf16.h>

#define KNN 20
#define NEG_SLOPE 0.2f

constexpr int BB = 8;
constexpr int NN = 1024;
constexpr int MM = 1024;

typedef short bf16x8 __attribute__((ext_vector_type(8)));
typedef float f32x4 __attribute__((ext_vector_type(4)));
typedef double f64x4 __attribute__((ext_vector_type(4)));

// ================= top-20 selection (set-exact) =================
__device__ __forceinline__ unsigned pack_key(double d, int j) {
  float f = (float)d;
  unsigned u = __float_as_uint(f);
  u = (u & 0x80000000u) ? ~u : (u | 0x80000000u);
  return (u & ~1023u) | (unsigned)(1023 - j);
}

// Exact f64 reference path (tie semantics: larger value, tie -> lower idx).
__device__ __forceinline__ void topk_exact_f64(double (&v)[16], int lane, int* op) {
  for (int r = 0; r < KNN; ++r) {
    double bv = -INFINITY;
    int bj = MM;
#pragma unroll
    for (int m = 0; m < 16; ++m) {
      if (v[m] > bv) { bv = v[m]; bj = m * 64 + lane; }
    }
#pragma unroll
    for (int off = 32; off > 0; off >>= 1) {
      double ov = __shfl_xor(bv, off, 64);
      int oj = __shfl_xor(bj, off, 64);
      if (ov > bv || (ov == bv && oj < bj)) { bv = ov; bj = oj; }
    }
    if (bj < MM && lane == (bj & 63)) v[bj >> 6] = -INFINITY;
    if (lane == 0) op[r] = bj;
  }
}

// Fast path on 32-bit packed keys (22-bit monotone-f32 | inverted idx).
// Returns true if the 20/21 boundary is ambiguous at 22-bit granularity.
__device__ __forceinline__ bool topk20_fast(unsigned (&s)[16], int lane, int* op) {
  // Batcher odd-even mergesort, descending, fully unrolled (n=16)
#pragma unroll
  for (int p = 1; p < 16; p <<= 1) {
#pragma unroll
    for (int k = p; k >= 1; k >>= 1) {
#pragma unroll
      for (int j = k % p; j + k < 16; j += 2 * k) {
#pragma unroll
        for (int i = 0; i < k; ++i) {
          int a = j + i, b = j + i + k;
          if (b < 16 && (a / (2 * p)) == (b / (2 * p))) {
            unsigned hi = s[a] > s[b] ? s[a] : s[b];
            unsigned lo = s[a] > s[b] ? s[b] : s[a];
            s[a] = hi;
            s[b] = lo;
          }
        }
      }
    }
  }
  unsigned prev = 0;
#pragma unroll
  for (int r = 0; r < KNN; ++r) {
    unsigned win = s[0];
#pragma unroll
    for (int off = 32; off > 0; off >>= 1) {
      unsigned o = __shfl_xor(win, off, 64);
      win = o > win ? o : win;
    }
    if (lane == 0) op[r] = 1023 - (int)(win & 1023u);
    if (s[0] == win) {
#pragma unroll
      for (int i = 0; i < 15; ++i) s[i] = s[i + 1];
      s[15] = 0u;
    }
    prev = win;
  }
  unsigned win21 = s[0];
#pragma unroll
  for (int off = 32; off > 0; off >>= 1) {
    unsigned o = __shfl_xor(win21, off, 64);
    win21 = o > win21 ? o : win21;
  }
  return (prev >> 10) == (win21 >> 10);
}

// ======== f64 MFMA layout self-probe (one wave) ========
// P1: A=lane&15, B=1   -> D[i][j] = 4*i  (A-side row class per (lane,reg))
// P2: A=1, B=lane&15   -> D[i][j] = 4*j  (B-side col class)
// P3: A=3^(lane>>4), B=5^(lane>>4) -> sum_k 15^k = 3616 (channel pairing)
__global__ void k_probe_mfma(double* __restrict__ p) {
  int lane = threadIdx.x & 63;
  f64x4 z = {0.0, 0.0, 0.0, 0.0};
  double ai = (double)(lane & 15);
  double p3 = 1.0, p5 = 1.0;
  int kq = lane >> 4;
  for (int t = 0; t < kq; ++t) { p3 *= 3.0; p5 *= 5.0; }
  f64x4 d1 = __builtin_amdgcn_mfma_f64_16x16x4f64(ai, 1.0, z, 0, 0, 0);
  f64x4 d2 = __builtin_amdgcn_mfma_f64_16x16x4f64(1.0, ai, z, 0, 0, 0);
  f64x4 d3 = __builtin_amdgcn_mfma_f64_16x16x4f64(p3, p5, z, 0, 0, 0);
#pragma unroll
  for (int r = 0; r < 4; ++r) {
    p[lane * 4 + r] = d1[r];
    p[256 + lane * 4 + r] = d2[r];
    p[512 + lane * 4 + r] = d3[r];
  }
}

// Decode probes into per-(lane,reg) row/col tables; flag=1 only if everything
// validates exactly (integrality, range, pairing, bijectivity).
__global__ void k_probe_decode(const double* __restrict__ p, int* __restrict__ rowt,
                               int* __restrict__ colt, int* __restrict__ flag) {
  if (threadIdx.x != 0 || blockIdx.x != 0) return;
  unsigned char seen[256];
  for (int e = 0; e < 256; ++e) seen[e] = 0;
  bool ok = true;
  for (int e = 0; e < 256 && ok; ++e) {
    double va = p[e], vb = p[256 + e], vp = p[512 + e];
    int i = (int)(va * 0.25);
    int j = (int)(vb * 0.25);
    ok = (i >= 0) && (i < 16) && (j >= 0) && (j < 16) && (va == 4.0 * (double)i) &&
         (vb == 4.0 * (double)j) && (vp == 3616.0) && (seen[i * 16 + j] == 0);
    if (ok) {
      seen[i * 16 + j] = 1;
      rowt[e] = i;
      colt[e] = j;
    }
  }
  *flag = ok ? 1 : 0;
}

// ---------------- transpose f32 -> f64: (B,C,Np) -> (B,Np,C) ----------------
__global__ __launch_bounds__(256) void k_transpose_d(
    const float* __restrict__ in, double* __restrict__ out, int C, int Np) {
  int total = BB * C * Np;
  for (int t = blockIdx.x * 256 + threadIdx.x; t < total; t += gridDim.x * 256) {
    int c = t % C;
    int n = (t / C) % Np;
    int b = t / (C * Np);
    out[t] = (double)in[((size_t)b * C + c) * Np + n];
  }
}

// ---------------- f32 -> bf16 convert ----------------
__global__ __launch_bounds__(256) void k_cvt_bf16(
    const float* __restrict__ in, __hip_bfloat16* __restrict__ out, int n) {
  int i = blockIdx.x * 256 + threadIdx.x;
  if (i < n) out[i] = __float2bfloat16(in[i]);
}

// ------- per-point squared norm (RECIP=0) or reciprocal norm (RECIP=1), f64 -------
template <int RECIP>
__global__ __launch_bounds__(256) void k_rowsq(
    const double* __restrict__ A, int ld, int C, double* __restrict__ sq) {
  int p = blockIdx.x * 256 + threadIdx.x;
  if (p >= BB * NN) return;
  const double* row = A + (size_t)p * ld;
  double s = 0.0;
  for (int c = 0; c < C; ++c) { double v = row[c]; s += v * v; }
  if (RECIP) {
    sq[p] = 1.0 / fmax(sqrt(s), 1e-12);
  } else {
    sq[p] = s;
  }
}

// ---- fused L1 knn (C=3): all points in LDS (f64), f64 distances, fast topk ----
__global__ __launch_bounds__(256) void k_knn3(
    const double* __restrict__ xs3, const double* __restrict__ sq, int* __restrict__ idx) {
  __shared__ double P[NN * 3];
  int b = blockIdx.x;
  const double* Xb = xs3 + (size_t)b * NN * 3;
  int tid = threadIdx.x;
  for (int t = tid; t < NN * 3; t += 256) P[t] = Xb[t];
  __syncthreads();
  int wave = tid >> 6, lane = tid & 63;
  int i = blockIdx.y * 4 + wave;
  double xi = P[i * 3], yi = P[i * 3 + 1], zi = P[i * 3 + 2];
  double sqi = sq[b * NN + i];
  double v[16];
  unsigned s[16];
#pragma unroll
  for (int m = 0; m < 16; ++m) {
    int j = m * 64 + lane;
    double d = fma(xi, P[j * 3], 0.0);
    d = fma(yi, P[j * 3 + 1], d);
    d = fma(zi, P[j * 3 + 2], d);
    v[m] = 2.0 * d - sqi - sq[b * NN + j];
    s[m] = pack_key(v[m], j);
  }
  int* op = idx + ((size_t)b * NN + i) * KNN;
  if (topk20_fast(s, lane, op)) topk_exact_f64(v, lane, op);
}

// ---- unified gram: 64x64 tile / WG. If *flag: f64 MFMA path with probe-decoded
// D tables (robust to any D permutation). Else: verified VALU-FMA path (r14 inner).
// Writes packed keys ONLY. MODE 1: D = 2*dot - sqA_i - sqB_j ; MODE 2: dot*rnA*rnB
template <int MODE>
__global__ __launch_bounds__(256) void k_gram_u(
    const double* __restrict__ A, int lda, const double* __restrict__ Bm, int ldb,
    const double* __restrict__ sqA, const double* __restrict__ sqB,
    unsigned* __restrict__ kk, int C, int b0, const int* __restrict__ rowt,
    const int* __restrict__ colt, const int* __restrict__ flag) {
  __shared__ double As[16][66];
  __shared__ double Bs[16][66];
  int bg = b0 + blockIdx.x;
  int bl = blockIdx.x;
  int j0 = blockIdx.y * 64;
  int i0 = blockIdx.z * 64;
  const double* Ab = A + (size_t)bg * NN * lda;
  const double* Bb = Bm + (size_t)bg * MM * ldb;
  int tid = threadIdx.x;
  if (*flag) {
    int lane = tid & 63, w = tid >> 6;
    int lm = lane & 15, lq = lane >> 4;
    f64x4 acc[4] = {};
    for (int c0 = 0; c0 < C; c0 += 16) {
      if (c0) __syncthreads();
      for (int r = 0; r < 4; ++r) {
        int li = tid + r * 256;
        int row = li >> 4, k = li & 15;
        As[k][row] = Ab[(size_t)(i0 + row) * lda + c0 + k];
        Bs[k][row] = Bb[(size_t)(j0 + row) * ldb + c0 + k];
      }
      __syncthreads();
#pragma unroll
      for (int kc = 0; kc < 4; ++kc) {
        double a = As[kc * 4 + lq][w * 16 + lm];
#pragma unroll
        for (int t = 0; t < 4; ++t) {
          double b = Bs[kc * 4 + lq][t * 16 + lm];
          acc[t] = __builtin_amdgcn_mfma_f64_16x16x4f64(a, b, acc[t], 0, 0, 0);
        }
      }
    }
    int rta[4], cta[4];
#pragma unroll
    for (int r = 0; r < 4; ++r) {
      rta[r] = rowt[lane * 4 + r];
      cta[r] = colt[lane * 4 + r];
    }
#pragma unroll
    for (int t = 0; t < 4; ++t) {
#pragma unroll
      for (int r = 0; r < 4; ++r) {
        int i = i0 + w * 16 + rta[r];
        int j = j0 + t * 16 + cta[r];
        double v = acc[t][r];
        if (MODE == 1) v = 2.0 * v - sqA[(size_t)bg * NN + i] - sqB[(size_t)bg * MM + j];
        if (MODE == 2) v = v * sqA[(size_t)bg * NN + i] * sqB[(size_t)bg * MM + j];
        kk[((size_t)bl * NN + i) * MM + j] = pack_key(v, j);
      }
    }
  } else {
    int tx = tid & 15, ty = tid >> 4;
    double acc[4][4] = {};
    for (int c0 = 0; c0 < C; c0 += 16) {
      if (c0) __syncthreads();
      for (int r = 0; r < 4; ++r) {
        int li = tid + r * 256;
        int row = li >> 4, k = li & 15;
        As[k][row] = Ab[(size_t)(i0 + row) * lda + c0 + k];
        Bs[k][row] = Bb[(size_t)(j0 + row) * ldb + c0 + k];
      }
      __syncthreads();
#pragma unroll
      for (int k = 0; k < 16; ++k) {
        double a_[4], b_[4];
#pragma unroll
        for (int ii = 0; ii < 4; ++ii) a_[ii] = As[k][ty * 4 + ii];
#pragma unroll
        for (int jj = 0; jj < 4; ++jj) b_[jj] = Bs[k][jj * 16 + tx];
#pragma unroll
        for (int ii = 0; ii < 4; ++ii)
#pragma unroll
          for (int jj = 0; jj < 4; ++jj)
            acc[ii][jj] = fma(a_[ii], b_[jj], acc[ii][jj]);
      }
    }
    for (int ii = 0; ii < 4; ++ii) {
      int i = i0 + ty * 4 + ii;
      double qa = sqA[(size_t)bg * NN + i];
      for (int jj = 0; jj < 4; ++jj) {
        int j = j0 + jj * 16 + tx;
        double v = acc[ii][jj];
        if (MODE == 1) v = 2.0 * v - qa - sqB[(size_t)bg * MM + j];
        if (MODE == 2) v = v * qa * sqB[(size_t)bg * MM + j];
        kk[((size_t)bl * NN + i) * MM + j] = pack_key(v, j);
      }
    }
  }
}

// ------- top-20 per row from packed keys; exact-f64 RECOMPUTE fallback on tie -------
template <int MODE>
__global__ __launch_bounds__(256) void k_topk(
    const unsigned* __restrict__ kk, const double* __restrict__ A, int lda,
    const double* __restrict__ Bm, int ldb, const double* __restrict__ sqA,
    const double* __restrict__ sqB, int C, int* __restrict__ idx, int b0) {
  int wave = threadIdx.x >> 6;
  int lane = threadIdx.x & 63;
  int bl = blockIdx.x;
  int bg = b0 + bl;
  int row = blockIdx.y * 4 + wave;
  const unsigned* rp = kk + ((size_t)bl * NN + row) * MM;
  unsigned s[16];
#pragma unroll
  for (int m = 0; m < 16; ++m) s[m] = rp[m * 64 + lane];
  int* op = idx + ((size_t)bg * NN + row) * KNN;
  if (topk20_fast(s, lane, op)) {
    // ambiguous boundary: recompute exact f64 distances for this row from features
    const double* ar = A + ((size_t)bg * NN + row) * lda;
    const double* Bb = Bm + (size_t)bg * MM * ldb;
    double qa = sqA[(size_t)bg * NN + row];
    double v[16];
#pragma unroll
    for (int m = 0; m < 16; ++m) v[m] = 0.0;
    for (int c = 0; c < C; ++c) {
      double av = ar[c];
#pragma unroll
      for (int m = 0; m < 16; ++m)
        v[m] = fma(av, Bb[(size_t)(m * 64 + lane) * ldb + c], v[m]);
    }
#pragma unroll
    for (int m = 0; m < 16; ++m) {
      double qb = sqB[(size_t)bg * MM + m * 64 + lane];
      if (MODE == 1) v[m] = 2.0 * v[m] - qa - qb;
      if (MODE == 2) v[m] = v[m] * qa * qb;
    }
    topk_exact_f64(v, lane, op);
  }
}

// --- fused per-point feature matmul (f64), both modes in one launch ---
// mode 0: out0[b,j,o] = sum_c src0[b,j,c]*w[o,c]
// mode 1: out1[b,j,o] = sum_c src1[b,j,c]*(w[o,C+c]-w[o,c])
__global__ __launch_bounds__(256) void k_featmm2(
    const double* __restrict__ src0, int ld0, int Np0,
    const double* __restrict__ src1, int ld1,
    const float* __restrict__ w, int CW,
    double* __restrict__ out0, double* __restrict__ out1, int C, int O) {
  __shared__ double As[16][68];
  __shared__ double Ws[16][68];
  int nbo = O >> 6;
  int b = blockIdx.x;
  int mode = blockIdx.y >= nbo;
  int o0 = (blockIdx.y - (mode ? nbo : 0)) * 64;
  int j0 = blockIdx.z * 64;
  const double* src = mode ? src1 : src0;
  int lds_ = mode ? ld1 : ld0;
  int Np = mode ? NN : Np0;
  double* out = mode ? out1 : out0;
  int tx = threadIdx.x, ty = threadIdx.y;
  int tid = ty * 16 + tx;
  const double* Sb = src + (size_t)b * Np * lds_;
  double acc[4][4] = {};
  for (int c0 = 0; c0 < C; c0 += 16) {
    for (int r = 0; r < 4; ++r) {
      int li = tid + r * 256;
      int row = li >> 4, k = li & 15;
      int c = c0 + k;
      As[k][row] = (c < C) ? Sb[(size_t)(j0 + row) * lds_ + c] : 0.0;
      double wv = 0.0;
      if (c < C) {
        const float* wr = w + (size_t)(o0 + row) * CW;
        wv = (mode == 0) ? (double)wr[c] : ((double)wr[C + c] - (double)wr[c]);
      }
      Ws[k][row] = wv;
    }
    __syncthreads();
#pragma unroll
    for (int k = 0; k < 16; ++k) {
      double a_[4], b_[4];
#pragma unroll
      for (int ii = 0; ii < 4; ++ii) a_[ii] = As[k][ty * 4 + ii];
#pragma unroll
      for (int jj = 0; jj < 4; ++jj) b_[jj] = Ws[k][tx * 4 + jj];
#pragma unroll
      for (int ii = 0; ii < 4; ++ii)
#pragma unroll
        for (int jj = 0; jj < 4; ++jj)
          acc[ii][jj] = fma(a_[ii], b_[jj], acc[ii][jj]);
    }
    __syncthreads();
  }
  for (int ii = 0; ii < 4; ++ii) {
    int j = j0 + ty * 4 + ii;
    double* op = &out[((size_t)b * Np + j) * O + o0 + tx * 4];
    double2 v0, v1;
    v0.x = acc[ii][0];
    v0.y = acc[ii][1];
    v1.x = acc[ii][2];
    v1.y = acc[ii][3];
    *(double2*)op = v0;
    *(double2*)(op + 2) = v1;
  }
}

// ---- layer-5 GEMM via bf16 MFMA: per-wave 16x16 tile, frags direct from global ----
__global__ __launch_bounds__(256) void k_gemm5_mfma(
    const __hip_bfloat16* __restrict__ cath, const __hip_bfloat16* __restrict__ w5h,
    float* __restrict__ out) {
  int b = blockIdx.x;
  int j0 = blockIdx.y * 16;
  int o0 = blockIdx.z * 64 + (threadIdx.x >> 6) * 16;
  int lane = threadIdx.x & 63;
  int m = lane & 15;
  int quad = lane >> 4;
  const __hip_bfloat16* arow = cath + ((size_t)b * NN + j0 + m) * 512 + quad * 8;
  const __hip_bfloat16* brow = w5h + (size_t)(o0 + m) * 512 + quad * 8;
  f32x4 acc = {0.f, 0.f, 0.f, 0.f};
#pragma unroll
  for (int c0 = 0; c0 < 512; c0 += 32) {
    bf16x8 a = *(const bf16x8*)(arow + c0);
    bf16x8 bb = *(const bf16x8*)(brow + c0);
    acc = __builtin_amdgcn_mfma_f32_16x16x32_bf16(a, bb, acc, 0, 0, 0);
  }
  float* obase = &out[((size_t)b * NN + j0 + quad * 4) * 512 + o0 + m];
#pragma unroll
  for (int r = 0; r < 4; ++r) obase[(size_t)r * 512] = acc[r];
}

// ------- fused gather (f64): per (n,o) max_k y, accumulate BN stats -------
__global__ __launch_bounds__(256) void k_gather(
    const double* __restrict__ u, const double* __restrict__ t, const int* __restrict__ idx,
    double* __restrict__ stats, double* __restrict__ mx, int O, int srcNp) {
  __shared__ int lidx[16 * KNN];
  __shared__ double rs[256];
  __shared__ double rq[256];
  int b = blockIdx.x;
  int n0 = blockIdx.y * 16;
  int o0 = blockIdx.z * 64;
  int tid = threadIdx.x;
  int lane = tid & 63, nsl = tid >> 6;
  for (int w = tid; w < 16 * KNN; w += 256)
    lidx[w] = idx[((size_t)b * NN + n0) * KNN + w];
  __syncthreads();
  int oo = o0 + lane;
  double s1 = 0.0, s2 = 0.0;
  for (int ns = nsl; ns < 16; ns += 4) {
    size_t row = (size_t)b * NN + n0 + ns;
    double tv = t[row * O + oo];
    double mxv = -INFINITY;
    double a1 = 0.0, a2 = 0.0;
#pragma unroll
    for (int k = 0; k < KNN; ++k) {
      int j = lidx[ns * KNN + k];
      double yv = u[((size_t)b * srcNp + j) * O + oo] + tv;
      mxv = fmax(mxv, yv);
      a1 += yv;
      a2 = fma(yv, yv, a2);
    }
    mx[row * O + oo] = mxv;
    s1 += a1;
    s2 += a2;
  }
  rs[tid] = s1;
  rq[tid] = s2;
  __syncthreads();
  if (tid < 64) {
    s1 = rs[tid] + rs[tid + 64] + rs[tid + 128] + rs[tid + 192];
    s2 = rq[tid] + rq[tid + 64] + rq[tid + 128] + rq[tid + 192];
    atomicAdd(&stats[o0 + tid], s1);
    atomicAdd(&stats[O + o0 + tid], s2);
  }
}

// ---------------- fold BN into per-channel scale/shift (f64) ----------------
__global__ void k_bnfin(const double* __restrict__ stats, const float* __restrict__ gamma,
                        const float* __restrict__ beta, double* __restrict__ sc,
                        int O, double cnt) {
  int o = threadIdx.x;
  if (o >= O) return;
  double mean = stats[o] / cnt;
  double var = stats[O + o] / cnt - mean * mean;
  if (var < 0.0) var = 0.0;
  double rstd = 1.0 / sqrt(var + 1e-5);
  double s = (double)gamma[o] * rstd;
  double c = (double)beta[o] - mean * s;
  sc[o] = s;
  sc[O + o] = c;
}

// --- apply BN+lrelu to stored max (f64); write catd (f64, knn channels) + bf16 ---
__global__ __launch_bounds__(256) void k_bnapply(
    const double* __restrict__ mx, const double* __restrict__ u, const double* __restrict__ t,
    const int* __restrict__ idx, const double* __restrict__ sc, double* __restrict__ catd,
    __hip_bfloat16* __restrict__ cath, int coff, int O, int srcNp) {
  int i = blockIdx.x * 256 + threadIdx.x;
  int total = BB * NN * O;
  if (i >= total) return;
  int oo = i % O;
  int n = (i / O) % NN;
  int b = i / (O * NN);
  double s = sc[oo], c = sc[O + oo];
  double v;
  if (s >= 0.0) {
    v = mx[i];
  } else {  // monotone-decreasing transform needs min_k y (never hit with gamma=1)
    double tv = t[i];
    double mn = INFINITY;
    for (int k = 0; k < KNN; ++k) {
      int j = idx[((size_t)b * NN + n) * KNN + k];
      mn = fmin(mn, u[((size_t)b * srcNp + j) * O + oo] + tv);
    }
    v = mn;
  }
  double a = s * v + c;
  a = (a >= 0.0) ? a : 0.2 * a;
  size_t ci = ((size_t)b * NN + n) * 512 + coff + oo;
  cath[ci] = __float2bfloat16((float)a);
  if (coff < 256) catd[((size_t)b * NN + n) * 256 + coff + oo] = a;
}

// ------- layer 5 streaming stats over stored y5 (B,N,512) -------
__global__ __launch_bounds__(256) void k_stats512(
    const float* __restrict__ y5, double* __restrict__ stats) {
  int b = blockIdx.y;
  int n0 = blockIdx.x * 32;
  int tid = threadIdx.x;
  for (int part = 0; part < 2; ++part) {
    int oo = tid + part * 256;
    float a1 = 0.f, a2 = 0.f;
    for (int ns = 0; ns < 32; ++ns) {
      float v = y5[((size_t)b * NN + n0 + ns) * 512 + oo];
      a1 += v;
      a2 = fmaf(v, v, a2);
    }
    atomicAdd(&stats[oo], (double)a1);
    atomicAdd(&stats[512 + oo], (double)a2);
  }
}

// ------- layer 5 finalize: BN+lrelu on stored y5, transpose, f32 store -------
__global__ __launch_bounds__(256) void k_final5b(
    const float* __restrict__ y5, const double* __restrict__ sc, float* __restrict__ out) {
  __shared__ float tile[64][65];
  int b = blockIdx.z;
  int n0 = blockIdx.x * 64;
  int o0 = blockIdx.y * 64;
  int tid = threadIdx.x;
  for (int r = 0; r < 16; ++r) {
    int li = tid + r * 256;
    int nl = li >> 6, ol = li & 63;
    float v = y5[((size_t)b * NN + n0 + nl) * 512 + o0 + ol];
    float a = (float)(sc[o0 + ol] * (double)v + sc[512 + o0 + ol]);
    a = (a >= 0.f) ? a : NEG_SLOPE * a;
    tile[nl][ol] = a;
  }
  __syncthreads();
  for (int r = 0; r < 16; ++r) {
    int li = tid + r * 256;
    int ol = li >> 6, nl = li & 63;
    out[((size_t)b * 512 + o0 + ol) * NN + n0 + nl] = tile[nl][ol];
  }
}

// =====================================================================================
// r16: r15's f64-MFMA gram failed (absmax 8.3 = broadly wrong neighbor sets); every
// other r14->r15 delta audits clean, so the v_mfma_f64_16x16x4 fragment-layout guess
// is the suspect (that shape was never HW-verified, unlike the modern 16x16 shapes).
// This round adds a 3-probe MFMA self-test: decodes the TRUE per-(lane,reg) D row/col
// tables, validates A/B placement + channel pairing + bijectivity exactly. Gram uses
// the MFMA path with decoded tables only if the probe fully validates; else falls back
// to the r14-verified VALU-FMA inner loop in the same kernel. Keys-only epilogue and
// recompute-fallback topk retained. Passes either way; perf tells which path engaged.
extern "C" void kernel_launch(void* const* d_in, const int* in_sizes, int n_in,
                              void* d_out, int out_size, void* d_ws, size_t ws_size,
                              hipStream_t stream) {
  const float* x = (const float*)d_in[0];
  const float* y = (const float*)d_in[1];
  const float* w1 = (const float*)d_in[2];
  const float* w2 = (const float*)d_in[3];
  const float* w3 = (const float*)d_in[4];
  const float* w4 = (const float*)d_in[5];
  const float* w5 = (const float*)d_in[6];
  const float* g1 = (const float*)d_in[7];
  const float* b1 = (const float*)d_in[8];
  const float* g2 = (const float*)d_in[9];
  const float* b2 = (const float*)d_in[10];
  const float* g3 = (const float*)d_in[11];
  const float* b3 = (const float*)d_in[12];
  const float* g4 = (const float*)d_in[13];
  const float* b4 = (const float*)d_in[14];
  const float* g5 = (const float*)d_in[15];
  const float* b5 = (const float*)d_in[16];

  char* base = (char*)d_ws;
  size_t off = 0;
  auto alloc = [&](size_t bytes) -> char* {
    char* p = base + off;
    off += (bytes + 255) & ~(size_t)255;
    return p;
  };
  double* st = (double*)alloc(1024 * 8);
  double* sc = (double*)alloc(1024 * 8);
  double* sq = (double*)alloc((size_t)BB * NN * 8);
  double* rnx = (double*)alloc((size_t)BB * NN * 8);
  double* rny = (double*)alloc((size_t)BB * MM * 8);
  int* idxb = (int*)alloc((size_t)BB * NN * KNN * 4);
  double* pout = (double*)alloc(3 * 256 * 8);
  int* rowt = (int*)alloc(256 * 4);
  int* colt = (int*)alloc(256 * 4);
  int* pflag = (int*)alloc(256);
  double* xs3d = (double*)alloc((size_t)BB * NN * 3 * 8);
  double* ysd = (double*)alloc((size_t)BB * MM * 128 * 8);
  double* catd = (double*)alloc((size_t)BB * NN * 256 * 8);  // knn channels 0..255
  __hip_bfloat16* cath = (__hip_bfloat16*)alloc((size_t)BB * NN * 512 * 2);
  __hip_bfloat16* w5h = (__hip_bfloat16*)alloc((size_t)512 * 512 * 2);
  double* uu = (double*)alloc((size_t)BB * MM * 256 * 8);  // src term (max O=256)
  double* tt = (double*)alloc((size_t)BB * NN * 256 * 8);  // center term
  size_t kkBatchBytes = (size_t)NN * MM * 4;  // 4 MB per batch (keys)
  size_t avail = (ws_size > off) ? (ws_size - off) : 0;
  int CB = (int)(avail / kkBatchBytes);
  if (CB < 1) CB = 1;
  if (CB > BB) CB = BB;
  unsigned* KK = (unsigned*)alloc((size_t)CB * kkBatchBytes);
  float* y5 = (float*)uu;             // layer-5 pre-BN (16MB), uu dead by then
  double* mx = (double*)d_out;        // max_k y (f64, <=16MB == out_size)
  float* outp = (float*)d_out;

  const dim3 blk2(16, 16);
  const double cntE = (double)BB * NN * KNN;

  auto knn = [&](const double* A, int lda, const double* Bm, int ldb,
                 const double* sa, const double* sb, int C, int mode) {
    for (int b0 = 0; b0 < BB; b0 += CB) {
      int cb = (BB - b0 < CB) ? (BB - b0) : CB;
      dim3 g(cb, MM / 64, NN / 64);
      if (mode == 1) {
        k_gram_u<1><<<g, 256, 0, stream>>>(A, lda, Bm, ldb, sa, sb, KK, C, b0, rowt,
                                           colt, pflag);
        k_topk<1><<<dim3(cb, 256), 256, 0, stream>>>(KK, A, lda, Bm, ldb, sa, sb, C,
                                                     idxb, b0);
      } else {
        k_gram_u<2><<<g, 256, 0, stream>>>(A, lda, Bm, ldb, sa, sb, KK, C, b0, rowt,
                                           colt, pflag);
        k_topk<2><<<dim3(cb, 256), 256, 0, stream>>>(KK, A, lda, Bm, ldb, sa, sb, C,
                                                     idxb, b0);
      }
    }
  };

  auto edge_layer = [&](const double* ctr, int ldc, const double* src, int ldsrc,
                        int srcNp, const float* w, int CW, const float* g,
                        const float* bb, int C, int O, int coff) {
    k_featmm2<<<dim3(8, 2 * (O / 64), 16), blk2, 0, stream>>>(src, ldsrc, srcNp, ctr,
                                                              ldc, w, CW, uu, tt, C, O);
    hipMemsetAsync(st, 0, 1024 * 8, stream);
    k_gather<<<dim3(BB, NN / 16, O / 64), 256, 0, stream>>>(uu, tt, idxb, st, mx, O,
                                                            srcNp);
    k_bnfin<<<1, O, 0, stream>>>(st, g, bb, sc, O, cntE);
    k_bnapply<<<(BB * NN * O + 255) / 256, 256, 0, stream>>>(mx, uu, tt, idxb, sc, catd,
                                                             cath, coff, O, srcNp);
  };

  // ---- f64-MFMA layout probe + input transposes (f64) + w5 bf16 convert ----
  k_probe_mfma<<<1, 64, 0, stream>>>(pout);
  k_probe_decode<<<1, 1, 0, stream>>>(pout, rowt, colt, pflag);
  k_transpose_d<<<96, 256, 0, stream>>>(x, xs3d, 3, NN);
  k_transpose_d<<<2048, 256, 0, stream>>>(y, ysd, 128, MM);
  k_cvt_bf16<<<1024, 256, 0, stream>>>(w5, w5h, 512 * 512);

  // ---- layer 1: C=3, O=64 (fused knn, no gram) ----
  k_rowsq<0><<<32, 256, 0, stream>>>(xs3d, 3, 3, sq);
  k_knn3<<<dim3(BB, 256), 256, 0, stream>>>(xs3d, sq, idxb);
  edge_layer(xs3d, 3, xs3d, 3, NN, w1, 6, g1, b1, 3, 64, 0);

  // ---- layer 2: x1 = catd[:,0:64], C=64, O=64 ----
  k_rowsq<0><<<32, 256, 0, stream>>>(catd, 256, 64, sq);
  knn(catd, 256, catd, 256, sq, sq, 64, 1);
  edge_layer(catd, 256, catd, 256, NN, w2, 128, g2, b2, 64, 64, 64);

  // ---- layer 3: x2 = catd[:,64:128], C=64, O=128 ----
  k_rowsq<0><<<32, 256, 0, stream>>>(catd + 64, 256, 64, sq);
  knn(catd + 64, 256, catd + 64, 256, sq, sq, 64, 1);
  edge_layer(catd + 64, 256, catd + 64, 256, NN, w3, 128, g3, b3, 64, 128, 128);

  // ---- layer 4 (IA): x3 = catd[:,128:256], src = y (cosine knn), C=128, O=256 ----
  k_rowsq<1><<<32, 256, 0, stream>>>(catd + 128, 256, 128, rnx);
  k_rowsq<1><<<32, 256, 0, stream>>>(ysd, 128, 128, rny);
  knn(catd + 128, 256, ysd, 128, rnx, rny, 128, 2);
  edge_layer(catd + 128, 256, ysd, 128, MM, w4, 256, g4, b4, 128, 256, 256);

  // ---- layer 5: bf16-MFMA GEMM -> y5 (aliases uu), BN over (B,N), lrelu, transpose ----
  hipMemsetAsync(st, 0, 1024 * 8, stream);
  k_gemm5_mfma<<<dim3(BB, 64, 8), 256, 0, stream>>>(cath, w5h, y5);
  k_stats512<<<dim3(32, 8), 256, 0, stream>>>(y5, st);
  k_bnfin<<<1, 512, 0, stream>>>(st, g5, b5, sc, 512, (double)(BB * NN));
  k_final5b<<<dim3(16, 8, 8), 256, 0, stream>>>(y5, sc, outp);
}

// Round 4
// 824.553 us; speedup vs baseline: 1.2309x; 1.2309x over previous
//
#include <hip/hip_runtime.h>
#include <hip/hip_bf16.h>

#define KNN 20
#define NEG_SLOPE 0.2f

constexpr int BB = 8;
constexpr int NN = 1024;
constexpr int MM = 1024;

typedef short bf16x8 __attribute__((ext_vector_type(8)));
typedef float f32x4 __attribute__((ext_vector_type(4)));
typedef double f64x4 __attribute__((ext_vector_type(4)));
typedef unsigned long long u64;

// ================= top-20 selection via exact u64 keys =================
// Monotone f64->u64 map, low 10 bits replaced by inverted column index.
// Key order == f64 descending order with tie -> lower idx (jax top_k semantics),
// up to 2^-43 relative granularity (far below the f64-pipeline noise floor).
__device__ __forceinline__ u64 pack_key64(double d, int j) {
  u64 u = (u64)__double_as_longlong(d);
  u = (u & 0x8000000000000000ULL) ? ~u : (u | 0x8000000000000000ULL);
  return (u & ~(u64)1023) | (u64)(1023 - j);
}

// Per-wave top-20: each lane holds 16 keys; Batcher odd-even mergesort (desc),
// then 20 extraction rounds (wave-max + winner-lane shift). Exact, no fallback.
__device__ __forceinline__ void topk20_u64(u64 (&s)[16], int lane, int* op) {
#pragma unroll
  for (int p = 1; p < 16; p <<= 1) {
#pragma unroll
    for (int k = p; k >= 1; k >>= 1) {
#pragma unroll
      for (int j = k % p; j + k < 16; j += 2 * k) {
#pragma unroll
        for (int i = 0; i < k; ++i) {
          int a = j + i, b = j + i + k;
          if (b < 16 && (a / (2 * p)) == (b / (2 * p))) {
            u64 hi = s[a] > s[b] ? s[a] : s[b];
            u64 lo = s[a] > s[b] ? s[b] : s[a];
            s[a] = hi;
            s[b] = lo;
          }
        }
      }
    }
  }
#pragma unroll
  for (int r = 0; r < KNN; ++r) {
    u64 win = s[0];
#pragma unroll
    for (int off = 32; off > 0; off >>= 1) {
      u64 o = __shfl_xor(win, off, 64);
      win = o > win ? o : win;
    }
    if (lane == 0) op[r] = 1023 - (int)(win & (u64)1023);
    if (s[0] == win) {
#pragma unroll
      for (int i = 0; i < 15; ++i) s[i] = s[i + 1];
      s[15] = 0ULL;
    }
  }
}

// ======== f64 MFMA layout self-probe (one wave) ========
// P1: A=lane&15, B=1   -> D[i][j] = 4*i  (A-side row class per (lane,reg))
// P2: A=1, B=lane&15   -> D[i][j] = 4*j  (B-side col class)
// P3: A=3^(lane>>4), B=5^(lane>>4) -> sum_k 15^k = 3616 (channel pairing)
__global__ void k_probe_mfma(double* __restrict__ p) {
  int lane = threadIdx.x & 63;
  f64x4 z = {0.0, 0.0, 0.0, 0.0};
  double ai = (double)(lane & 15);
  double p3 = 1.0, p5 = 1.0;
  int kq = lane >> 4;
  for (int t = 0; t < kq; ++t) { p3 *= 3.0; p5 *= 5.0; }
  f64x4 d1 = __builtin_amdgcn_mfma_f64_16x16x4f64(ai, 1.0, z, 0, 0, 0);
  f64x4 d2 = __builtin_amdgcn_mfma_f64_16x16x4f64(1.0, ai, z, 0, 0, 0);
  f64x4 d3 = __builtin_amdgcn_mfma_f64_16x16x4f64(p3, p5, z, 0, 0, 0);
#pragma unroll
  for (int r = 0; r < 4; ++r) {
    p[lane * 4 + r] = d1[r];
    p[256 + lane * 4 + r] = d2[r];
    p[512 + lane * 4 + r] = d3[r];
  }
}

// Decode probes into per-(lane,reg) row/col tables; flag=1 only if everything
// validates exactly (integrality, range, pairing, bijectivity).
__global__ void k_probe_decode(const double* __restrict__ p, int* __restrict__ rowt,
                               int* __restrict__ colt, int* __restrict__ flag) {
  if (threadIdx.x != 0 || blockIdx.x != 0) return;
  unsigned char seen[256];
  for (int e = 0; e < 256; ++e) seen[e] = 0;
  bool ok = true;
  for (int e = 0; e < 256 && ok; ++e) {
    double va = p[e], vb = p[256 + e], vp = p[512 + e];
    int i = (int)(va * 0.25);
    int j = (int)(vb * 0.25);
    ok = (i >= 0) && (i < 16) && (j >= 0) && (j < 16) && (va == 4.0 * (double)i) &&
         (vb == 4.0 * (double)j) && (vp == 3616.0) && (seen[i * 16 + j] == 0);
    if (ok) {
      seen[i * 16 + j] = 1;
      rowt[e] = i;
      colt[e] = j;
    }
  }
  *flag = ok ? 1 : 0;
}

// ---------------- transpose f32 -> f64: (B,C,Np) -> (B,Np,C) ----------------
__global__ __launch_bounds__(256) void k_transpose_d(
    const float* __restrict__ in, double* __restrict__ out, int C, int Np) {
  int total = BB * C * Np;
  for (int t = blockIdx.x * 256 + threadIdx.x; t < total; t += gridDim.x * 256) {
    int c = t % C;
    int n = (t / C) % Np;
    int b = t / (C * Np);
    out[t] = (double)in[((size_t)b * C + c) * Np + n];
  }
}

// ---------------- f32 -> bf16 convert ----------------
__global__ __launch_bounds__(256) void k_cvt_bf16(
    const float* __restrict__ in, __hip_bfloat16* __restrict__ out, int n) {
  int i = blockIdx.x * 256 + threadIdx.x;
  if (i < n) out[i] = __float2bfloat16(in[i]);
}

// ------- per-point squared norm (RECIP=0) or reciprocal norm (RECIP=1), f64 -------
template <int RECIP>
__global__ __launch_bounds__(256) void k_rowsq(
    const double* __restrict__ A, int ld, int C, double* __restrict__ sq) {
  int p = blockIdx.x * 256 + threadIdx.x;
  if (p >= BB * NN) return;
  const double* row = A + (size_t)p * ld;
  double s = 0.0;
  for (int c = 0; c < C; ++c) { double v = row[c]; s += v * v; }
  if (RECIP) {
    sq[p] = 1.0 / fmax(sqrt(s), 1e-12);
  } else {
    sq[p] = s;
  }
}

// ---- fused L1 knn (C=3): all points in LDS (f64), u64-key topk (exact) ----
__global__ __launch_bounds__(256) void k_knn3(
    const double* __restrict__ xs3, const double* __restrict__ sq, int* __restrict__ idx) {
  __shared__ double P[NN * 3];
  int b = blockIdx.x;
  const double* Xb = xs3 + (size_t)b * NN * 3;
  int tid = threadIdx.x;
  for (int t = tid; t < NN * 3; t += 256) P[t] = Xb[t];
  __syncthreads();
  int wave = tid >> 6, lane = tid & 63;
  int i = blockIdx.y * 4 + wave;
  double xi = P[i * 3], yi = P[i * 3 + 1], zi = P[i * 3 + 2];
  double sqi = sq[b * NN + i];
  u64 s[16];
#pragma unroll
  for (int m = 0; m < 16; ++m) {
    int j = m * 64 + lane;
    double d = fma(xi, P[j * 3], 0.0);
    d = fma(yi, P[j * 3 + 1], d);
    d = fma(zi, P[j * 3 + 2], d);
    s[m] = pack_key64(2.0 * d - sqi - sq[b * NN + j], j);
  }
  int* op = idx + ((size_t)b * NN + i) * KNN;
  topk20_u64(s, lane, op);
}

// ---- unified gram: 64x64 tile / WG. If *flag: f64 MFMA path with probe-decoded
// D tables (robust to any D permutation). Else: verified VALU-FMA path.
// Writes exact u64 keys ONLY. MODE 1: D = 2*dot - sqA_i - sqB_j ; MODE 2: dot*rnA*rnB
template <int MODE>
__global__ __launch_bounds__(256) void k_gram_u(
    const double* __restrict__ A, int lda, const double* __restrict__ Bm, int ldb,
    const double* __restrict__ sqA, const double* __restrict__ sqB,
    u64* __restrict__ kk, int C, int b0, const int* __restrict__ rowt,
    const int* __restrict__ colt, const int* __restrict__ flag) {
  __shared__ double As[16][66];
  __shared__ double Bs[16][66];
  int bg = b0 + blockIdx.x;
  int bl = blockIdx.x;
  int j0 = blockIdx.y * 64;
  int i0 = blockIdx.z * 64;
  const double* Ab = A + (size_t)bg * NN * lda;
  const double* Bb = Bm + (size_t)bg * MM * ldb;
  int tid = threadIdx.x;
  if (*flag) {
    int lane = tid & 63, w = tid >> 6;
    int lm = lane & 15, lq = lane >> 4;
    f64x4 acc[4] = {};
    for (int c0 = 0; c0 < C; c0 += 16) {
      if (c0) __syncthreads();
      for (int r = 0; r < 4; ++r) {
        int li = tid + r * 256;
        int row = li >> 4, k = li & 15;
        As[k][row] = Ab[(size_t)(i0 + row) * lda + c0 + k];
        Bs[k][row] = Bb[(size_t)(j0 + row) * ldb + c0 + k];
      }
      __syncthreads();
#pragma unroll
      for (int kc = 0; kc < 4; ++kc) {
        double a = As[kc * 4 + lq][w * 16 + lm];
#pragma unroll
        for (int t = 0; t < 4; ++t) {
          double b = Bs[kc * 4 + lq][t * 16 + lm];
          acc[t] = __builtin_amdgcn_mfma_f64_16x16x4f64(a, b, acc[t], 0, 0, 0);
        }
      }
    }
    int rta[4], cta[4];
#pragma unroll
    for (int r = 0; r < 4; ++r) {
      rta[r] = rowt[lane * 4 + r];
      cta[r] = colt[lane * 4 + r];
    }
#pragma unroll
    for (int t = 0; t < 4; ++t) {
#pragma unroll
      for (int r = 0; r < 4; ++r) {
        int i = i0 + w * 16 + rta[r];
        int j = j0 + t * 16 + cta[r];
        double v = acc[t][r];
        if (MODE == 1) v = 2.0 * v - sqA[(size_t)bg * NN + i] - sqB[(size_t)bg * MM + j];
        if (MODE == 2) v = v * sqA[(size_t)bg * NN + i] * sqB[(size_t)bg * MM + j];
        kk[((size_t)bl * NN + i) * MM + j] = pack_key64(v, j);
      }
    }
  } else {
    int tx = tid & 15, ty = tid >> 4;
    double acc[4][4] = {};
    for (int c0 = 0; c0 < C; c0 += 16) {
      if (c0) __syncthreads();
      for (int r = 0; r < 4; ++r) {
        int li = tid + r * 256;
        int row = li >> 4, k = li & 15;
        As[k][row] = Ab[(size_t)(i0 + row) * lda + c0 + k];
        Bs[k][row] = Bb[(size_t)(j0 + row) * ldb + c0 + k];
      }
      __syncthreads();
#pragma unroll
      for (int k = 0; k < 16; ++k) {
        double a_[4], b_[4];
#pragma unroll
        for (int ii = 0; ii < 4; ++ii) a_[ii] = As[k][ty * 4 + ii];
#pragma unroll
        for (int jj = 0; jj < 4; ++jj) b_[jj] = Bs[k][jj * 16 + tx];
#pragma unroll
        for (int ii = 0; ii < 4; ++ii)
#pragma unroll
          for (int jj = 0; jj < 4; ++jj)
            acc[ii][jj] = fma(a_[ii], b_[jj], acc[ii][jj]);
      }
    }
    for (int ii = 0; ii < 4; ++ii) {
      int i = i0 + ty * 4 + ii;
      double qa = sqA[(size_t)bg * NN + i];
      for (int jj = 0; jj < 4; ++jj) {
        int j = j0 + jj * 16 + tx;
        double v = acc[ii][jj];
        if (MODE == 1) v = 2.0 * v - qa - sqB[(size_t)bg * MM + j];
        if (MODE == 2) v = v * qa * sqB[(size_t)bg * MM + j];
        kk[((size_t)bl * NN + i) * MM + j] = pack_key64(v, j);
      }
    }
  }
}

// ------- top-20 per row from exact u64 keys; no fallback -------
__global__ __launch_bounds__(256) void k_topk(const u64* __restrict__ kk,
                                              int* __restrict__ idx, int b0) {
  int wave = threadIdx.x >> 6;
  int lane = threadIdx.x & 63;
  int bl = blockIdx.x;
  int row = blockIdx.y * 4 + wave;
  const u64* rp = kk + ((size_t)bl * NN + row) * MM;
  u64 s[16];
#pragma unroll
  for (int m = 0; m < 16; ++m) s[m] = rp[m * 64 + lane];
  int* op = idx + ((size_t)(b0 + bl) * NN + row) * KNN;
  topk20_u64(s, lane, op);
}

// --- fused per-point feature matmul (f64), both modes in one launch ---
// mode 0: out0[b,j,o] = sum_c src0[b,j,c]*w[o,c]
// mode 1: out1[b,j,o] = sum_c src1[b,j,c]*(w[o,C+c]-w[o,c])
__global__ __launch_bounds__(256) void k_featmm2(
    const double* __restrict__ src0, int ld0, int Np0,
    const double* __restrict__ src1, int ld1,
    const float* __restrict__ w, int CW,
    double* __restrict__ out0, double* __restrict__ out1, int C, int O) {
  __shared__ double As[16][68];
  __shared__ double Ws[16][68];
  int nbo = O >> 6;
  int b = blockIdx.x;
  int mode = blockIdx.y >= nbo;
  int o0 = (blockIdx.y - (mode ? nbo : 0)) * 64;
  int j0 = blockIdx.z * 64;
  const double* src = mode ? src1 : src0;
  int lds_ = mode ? ld1 : ld0;
  int Np = mode ? NN : Np0;
  double* out = mode ? out1 : out0;
  int tx = threadIdx.x, ty = threadIdx.y;
  int tid = ty * 16 + tx;
  const double* Sb = src + (size_t)b * Np * lds_;
  double acc[4][4] = {};
  for (int c0 = 0; c0 < C; c0 += 16) {
    for (int r = 0; r < 4; ++r) {
      int li = tid + r * 256;
      int row = li >> 4, k = li & 15;
      int c = c0 + k;
      As[k][row] = (c < C) ? Sb[(size_t)(j0 + row) * lds_ + c] : 0.0;
      double wv = 0.0;
      if (c < C) {
        const float* wr = w + (size_t)(o0 + row) * CW;
        wv = (mode == 0) ? (double)wr[c] : ((double)wr[C + c] - (double)wr[c]);
      }
      Ws[k][row] = wv;
    }
    __syncthreads();
#pragma unroll
    for (int k = 0; k < 16; ++k) {
      double a_[4], b_[4];
#pragma unroll
      for (int ii = 0; ii < 4; ++ii) a_[ii] = As[k][ty * 4 + ii];
#pragma unroll
      for (int jj = 0; jj < 4; ++jj) b_[jj] = Ws[k][tx * 4 + jj];
#pragma unroll
      for (int ii = 0; ii < 4; ++ii)
#pragma unroll
        for (int jj = 0; jj < 4; ++jj)
          acc[ii][jj] = fma(a_[ii], b_[jj], acc[ii][jj]);
    }
    __syncthreads();
  }
  for (int ii = 0; ii < 4; ++ii) {
    int j = j0 + ty * 4 + ii;
    double* op = &out[((size_t)b * Np + j) * O + o0 + tx * 4];
    double2 v0, v1;
    v0.x = acc[ii][0];
    v0.y = acc[ii][1];
    v1.x = acc[ii][2];
    v1.y = acc[ii][3];
    *(double2*)op = v0;
    *(double2*)(op + 2) = v1;
  }
}

// ---- layer-5 GEMM via bf16 MFMA: per-wave 16x16 tile, frags direct from global ----
__global__ __launch_bounds__(256) void k_gemm5_mfma(
    const __hip_bfloat16* __restrict__ cath, const __hip_bfloat16* __restrict__ w5h,
    float* __restrict__ out) {
  int b = blockIdx.x;
  int j0 = blockIdx.y * 16;
  int o0 = blockIdx.z * 64 + (threadIdx.x >> 6) * 16;
  int lane = threadIdx.x & 63;
  int m = lane & 15;
  int quad = lane >> 4;
  const __hip_bfloat16* arow = cath + ((size_t)b * NN + j0 + m) * 512 + quad * 8;
  const __hip_bfloat16* brow = w5h + (size_t)(o0 + m) * 512 + quad * 8;
  f32x4 acc = {0.f, 0.f, 0.f, 0.f};
#pragma unroll
  for (int c0 = 0; c0 < 512; c0 += 32) {
    bf16x8 a = *(const bf16x8*)(arow + c0);
    bf16x8 bb = *(const bf16x8*)(brow + c0);
    acc = __builtin_amdgcn_mfma_f32_16x16x32_bf16(a, bb, acc, 0, 0, 0);
  }
  float* obase = &out[((size_t)b * NN + j0 + quad * 4) * 512 + o0 + m];
#pragma unroll
  for (int r = 0; r < 4; ++r) obase[(size_t)r * 512] = acc[r];
}

// ------- fused gather (f64): per (n,o) max_k y, accumulate BN stats -------
__global__ __launch_bounds__(256) void k_gather(
    const double* __restrict__ u, const double* __restrict__ t, const int* __restrict__ idx,
    double* __restrict__ stats, double* __restrict__ mx, int O, int srcNp) {
  __shared__ int lidx[16 * KNN];
  __shared__ double rs[256];
  __shared__ double rq[256];
  int b = blockIdx.x;
  int n0 = blockIdx.y * 16;
  int o0 = blockIdx.z * 64;
  int tid = threadIdx.x;
  int lane = tid & 63, nsl = tid >> 6;
  for (int w = tid; w < 16 * KNN; w += 256)
    lidx[w] = idx[((size_t)b * NN + n0) * KNN + w];
  __syncthreads();
  int oo = o0 + lane;
  double s1 = 0.0, s2 = 0.0;
  for (int ns = nsl; ns < 16; ns += 4) {
    size_t row = (size_t)b * NN + n0 + ns;
    double tv = t[row * O + oo];
    double mxv = -INFINITY;
    double a1 = 0.0, a2 = 0.0;
#pragma unroll
    for (int k = 0; k < KNN; ++k) {
      int j = lidx[ns * KNN + k];
      double yv = u[((size_t)b * srcNp + j) * O + oo] + tv;
      mxv = fmax(mxv, yv);
      a1 += yv;
      a2 = fma(yv, yv, a2);
    }
    mx[row * O + oo] = mxv;
    s1 += a1;
    s2 += a2;
  }
  rs[tid] = s1;
  rq[tid] = s2;
  __syncthreads();
  if (tid < 64) {
    s1 = rs[tid] + rs[tid + 64] + rs[tid + 128] + rs[tid + 192];
    s2 = rq[tid] + rq[tid + 64] + rq[tid + 128] + rq[tid + 192];
    atomicAdd(&stats[o0 + tid], s1);
    atomicAdd(&stats[O + o0 + tid], s2);
  }
}

// ---------------- fold BN into per-channel scale/shift (f64) ----------------
__global__ void k_bnfin(const double* __restrict__ stats, const float* __restrict__ gamma,
                        const float* __restrict__ beta, double* __restrict__ sc,
                        int O, double cnt) {
  int o = threadIdx.x;
  if (o >= O) return;
  double mean = stats[o] / cnt;
  double var = stats[O + o] / cnt - mean * mean;
  if (var < 0.0) var = 0.0;
  double rstd = 1.0 / sqrt(var + 1e-5);
  double s = (double)gamma[o] * rstd;
  double c = (double)beta[o] - mean * s;
  sc[o] = s;
  sc[O + o] = c;
}

// --- apply BN+lrelu to stored max (f64); write catd (f64, knn channels) + bf16 ---
__global__ __launch_bounds__(256) void k_bnapply(
    const double* __restrict__ mx, const double* __restrict__ u, const double* __restrict__ t,
    const int* __restrict__ idx, const double* __restrict__ sc, double* __restrict__ catd,
    __hip_bfloat16* __restrict__ cath, int coff, int O, int srcNp) {
  int i = blockIdx.x * 256 + threadIdx.x;
  int total = BB * NN * O;
  if (i >= total) return;
  int oo = i % O;
  int n = (i / O) % NN;
  int b = i / (O * NN);
  double s = sc[oo], c = sc[O + oo];
  double v;
  if (s >= 0.0) {
    v = mx[i];
  } else {  // monotone-decreasing transform needs min_k y (never hit with gamma=1)
    double tv = t[i];
    double mn = INFINITY;
    for (int k = 0; k < KNN; ++k) {
      int j = idx[((size_t)b * NN + n) * KNN + k];
      mn = fmin(mn, u[((size_t)b * srcNp + j) * O + oo] + tv);
    }
    v = mn;
  }
  double a = s * v + c;
  a = (a >= 0.0) ? a : 0.2 * a;
  size_t ci = ((size_t)b * NN + n) * 512 + coff + oo;
  cath[ci] = __float2bfloat16((float)a);
  if (coff < 256) catd[((size_t)b * NN + n) * 256 + coff + oo] = a;
}

// ------- layer 5 streaming stats over stored y5 (B,N,512) -------
__global__ __launch_bounds__(256) void k_stats512(
    const float* __restrict__ y5, double* __restrict__ stats) {
  int b = blockIdx.y;
  int n0 = blockIdx.x * 32;
  int tid = threadIdx.x;
  for (int part = 0; part < 2; ++part) {
    int oo = tid + part * 256;
    float a1 = 0.f, a2 = 0.f;
    for (int ns = 0; ns < 32; ++ns) {
      float v = y5[((size_t)b * NN + n0 + ns) * 512 + oo];
      a1 += v;
      a2 = fmaf(v, v, a2);
    }
    atomicAdd(&stats[oo], (double)a1);
    atomicAdd(&stats[512 + oo], (double)a2);
  }
}

// ------- layer 5 finalize: BN+lrelu on stored y5, transpose, f32 store -------
__global__ __launch_bounds__(256) void k_final5b(
    const float* __restrict__ y5, const double* __restrict__ sc, float* __restrict__ out) {
  __shared__ float tile[64][65];
  int b = blockIdx.z;
  int n0 = blockIdx.x * 64;
  int o0 = blockIdx.y * 64;
  int tid = threadIdx.x;
  for (int r = 0; r < 16; ++r) {
    int li = tid + r * 256;
    int nl = li >> 6, ol = li & 63;
    float v = y5[((size_t)b * NN + n0 + nl) * 512 + o0 + ol];
    float a = (float)(sc[o0 + ol] * (double)v + sc[512 + o0 + ol]);
    a = (a >= 0.f) ? a : NEG_SLOPE * a;
    tile[nl][ol] = a;
  }
  __syncthreads();
  for (int r = 0; r < 16; ++r) {
    int li = tid + r * 256;
    int ol = li >> 6, nl = li & 63;
    out[((size_t)b * 512 + o0 + ol) * NN + n0 + nl] = tile[nl][ol];
  }
}

// =====================================================================================
// r17: r16's k_topk was 151us/launch (1.7% HBM, 4% occupancy) -- the exact-f64
// RECOMPUTE fallback (column-strided feature loads, serial chains) fired often enough
// (22-bit key ambiguity ~ rel gap < 1.2e-4) to dominate. Fix: u64 keys = monotone(f64)
// with low 10 bits replaced by inverted idx -> key order IS f64 descending with
// tie->lower-idx (jax semantics) at 2^-43 granularity. Fallback DELETED everywhere;
// k_topk is a pure streaming u64 Batcher sort. Gram key writes double (32->64 MB/layer,
// ~+5us) -- net ~-400us. Probe-gated MFMA/FMA dual gram retained (verified r16).
extern "C" void kernel_launch(void* const* d_in, const int* in_sizes, int n_in,
                              void* d_out, int out_size, void* d_ws, size_t ws_size,
                              hipStream_t stream) {
  const float* x = (const float*)d_in[0];
  const float* y = (const float*)d_in[1];
  const float* w1 = (const float*)d_in[2];
  const float* w2 = (const float*)d_in[3];
  const float* w3 = (const float*)d_in[4];
  const float* w4 = (const float*)d_in[5];
  const float* w5 = (const float*)d_in[6];
  const float* g1 = (const float*)d_in[7];
  const float* b1 = (const float*)d_in[8];
  const float* g2 = (const float*)d_in[9];
  const float* b2 = (const float*)d_in[10];
  const float* g3 = (const float*)d_in[11];
  const float* b3 = (const float*)d_in[12];
  const float* g4 = (const float*)d_in[13];
  const float* b4 = (const float*)d_in[14];
  const float* g5 = (const float*)d_in[15];
  const float* b5 = (const float*)d_in[16];

  char* base = (char*)d_ws;
  size_t off = 0;
  auto alloc = [&](size_t bytes) -> char* {
    char* p = base + off;
    off += (bytes + 255) & ~(size_t)255;
    return p;
  };
  double* st = (double*)alloc(1024 * 8);
  double* sc = (double*)alloc(1024 * 8);
  double* sq = (double*)alloc((size_t)BB * NN * 8);
  double* rnx = (double*)alloc((size_t)BB * NN * 8);
  double* rny = (double*)alloc((size_t)BB * MM * 8);
  int* idxb = (int*)alloc((size_t)BB * NN * KNN * 4);
  double* pout = (double*)alloc(3 * 256 * 8);
  int* rowt = (int*)alloc(256 * 4);
  int* colt = (int*)alloc(256 * 4);
  int* pflag = (int*)alloc(256);
  double* xs3d = (double*)alloc((size_t)BB * NN * 3 * 8);
  double* ysd = (double*)alloc((size_t)BB * MM * 128 * 8);
  double* catd = (double*)alloc((size_t)BB * NN * 256 * 8);  // knn channels 0..255
  __hip_bfloat16* cath = (__hip_bfloat16*)alloc((size_t)BB * NN * 512 * 2);
  __hip_bfloat16* w5h = (__hip_bfloat16*)alloc((size_t)512 * 512 * 2);
  double* uu = (double*)alloc((size_t)BB * MM * 256 * 8);  // src term (max O=256)
  double* tt = (double*)alloc((size_t)BB * NN * 256 * 8);  // center term
  size_t kkBatchBytes = (size_t)NN * MM * 8;  // 8 MB per batch (u64 keys)
  size_t avail = (ws_size > off) ? (ws_size - off) : 0;
  int CB = (int)(avail / kkBatchBytes);
  if (CB < 1) CB = 1;
  if (CB > BB) CB = BB;
  u64* KK = (u64*)alloc((size_t)CB * kkBatchBytes);
  float* y5 = (float*)uu;             // layer-5 pre-BN (16MB), uu dead by then
  double* mx = (double*)d_out;        // max_k y (f64, <=16MB == out_size)
  float* outp = (float*)d_out;

  const dim3 blk2(16, 16);
  const double cntE = (double)BB * NN * KNN;

  auto knn = [&](const double* A, int lda, const double* Bm, int ldb,
                 const double* sa, const double* sb, int C, int mode) {
    for (int b0 = 0; b0 < BB; b0 += CB) {
      int cb = (BB - b0 < CB) ? (BB - b0) : CB;
      dim3 g(cb, MM / 64, NN / 64);
      if (mode == 1)
        k_gram_u<1><<<g, 256, 0, stream>>>(A, lda, Bm, ldb, sa, sb, KK, C, b0, rowt,
                                           colt, pflag);
      else
        k_gram_u<2><<<g, 256, 0, stream>>>(A, lda, Bm, ldb, sa, sb, KK, C, b0, rowt,
                                           colt, pflag);
      k_topk<<<dim3(cb, 256), 256, 0, stream>>>(KK, idxb, b0);
    }
  };

  auto edge_layer = [&](const double* ctr, int ldc, const double* src, int ldsrc,
                        int srcNp, const float* w, int CW, const float* g,
                        const float* bb, int C, int O, int coff) {
    k_featmm2<<<dim3(8, 2 * (O / 64), 16), blk2, 0, stream>>>(src, ldsrc, srcNp, ctr,
                                                              ldc, w, CW, uu, tt, C, O);
    hipMemsetAsync(st, 0, 1024 * 8, stream);
    k_gather<<<dim3(BB, NN / 16, O / 64), 256, 0, stream>>>(uu, tt, idxb, st, mx, O,
                                                            srcNp);
    k_bnfin<<<1, O, 0, stream>>>(st, g, bb, sc, O, cntE);
    k_bnapply<<<(BB * NN * O + 255) / 256, 256, 0, stream>>>(mx, uu, tt, idxb, sc, catd,
                                                             cath, coff, O, srcNp);
  };

  // ---- f64-MFMA layout probe + input transposes (f64) + w5 bf16 convert ----
  k_probe_mfma<<<1, 64, 0, stream>>>(pout);
  k_probe_decode<<<1, 1, 0, stream>>>(pout, rowt, colt, pflag);
  k_transpose_d<<<96, 256, 0, stream>>>(x, xs3d, 3, NN);
  k_transpose_d<<<2048, 256, 0, stream>>>(y, ysd, 128, MM);
  k_cvt_bf16<<<1024, 256, 0, stream>>>(w5, w5h, 512 * 512);

  // ---- layer 1: C=3, O=64 (fused knn, no gram) ----
  k_rowsq<0><<<32, 256, 0, stream>>>(xs3d, 3, 3, sq);
  k_knn3<<<dim3(BB, 256), 256, 0, stream>>>(xs3d, sq, idxb);
  edge_layer(xs3d, 3, xs3d, 3, NN, w1, 6, g1, b1, 3, 64, 0);

  // ---- layer 2: x1 = catd[:,0:64], C=64, O=64 ----
  k_rowsq<0><<<32, 256, 0, stream>>>(catd, 256, 64, sq);
  knn(catd, 256, catd, 256, sq, sq, 64, 1);
  edge_layer(catd, 256, catd, 256, NN, w2, 128, g2, b2, 64, 64, 64);

  // ---- layer 3: x2 = catd[:,64:128], C=64, O=128 ----
  k_rowsq<0><<<32, 256, 0, stream>>>(catd + 64, 256, 64, sq);
  knn(catd + 64, 256, catd + 64, 256, sq, sq, 64, 1);
  edge_layer(catd + 64, 256, catd + 64, 256, NN, w3, 128, g3, b3, 64, 128, 128);

  // ---- layer 4 (IA): x3 = catd[:,128:256], src = y (cosine knn), C=128, O=256 ----
  k_rowsq<1><<<32, 256, 0, stream>>>(catd + 128, 256, 128, rnx);
  k_rowsq<1><<<32, 256, 0, stream>>>(ysd, 128, 128, rny);
  knn(catd + 128, 256, ysd, 128, rnx, rny, 128, 2);
  edge_layer(catd + 128, 256, ysd, 128, MM, w4, 256, g4, b4, 128, 256, 256);

  // ---- layer 5: bf16-MFMA GEMM -> y5 (aliases uu), BN over (B,N), lrelu, transpose ----
  hipMemsetAsync(st, 0, 1024 * 8, stream);
  k_gemm5_mfma<<<dim3(BB, 64, 8), 256, 0, stream>>>(cath, w5h, y5);
  k_stats512<<<dim3(32, 8), 256, 0, stream>>>(y5, st);
  k_bnfin<<<1, 512, 0, stream>>>(st, g5, b5, sc, 512, (double)(BB * NN));
  k_final5b<<<dim3(16, 8, 8), 256, 0, stream>>>(y5, sc, outp);
}

// Round 5
// 724.083 us; speedup vs baseline: 1.4017x; 1.1388x over previous
//
#include <hip/hip_runtime.h>
#include <hip/hip_bf16.h>

#define KNN 20
#define NEG_SLOPE 0.2f

constexpr int BB = 8;
constexpr int NN = 1024;
constexpr int MM = 1024;

typedef short bf16x8 __attribute__((ext_vector_type(8)));
typedef float f32x4 __attribute__((ext_vector_type(4)));
typedef double f64x4 __attribute__((ext_vector_type(4)));
typedef unsigned long long u64;

// ================= top-20 selection via exact u64 keys =================
// Monotone f64->u64 map, low 10 bits replaced by inverted column index.
// Key order == f64 descending order with tie -> lower idx (jax top_k semantics),
// up to 2^-43 relative granularity (far below the f64-pipeline noise floor).
__device__ __forceinline__ u64 pack_key64(double d, int j) {
  u64 u = (u64)__double_as_longlong(d);
  u = (u & 0x8000000000000000ULL) ? ~u : (u | 0x8000000000000000ULL);
  return (u & ~(u64)1023) | (u64)(1023 - j);
}

// Per-wave top-20: each lane holds 16 keys; Batcher odd-even mergesort (desc),
// then 20 extraction rounds (wave-max + winner-lane shift). Exact, no fallback.
__device__ __forceinline__ void topk20_u64(u64 (&s)[16], int lane, int* op) {
#pragma unroll
  for (int p = 1; p < 16; p <<= 1) {
#pragma unroll
    for (int k = p; k >= 1; k >>= 1) {
#pragma unroll
      for (int j = k % p; j + k < 16; j += 2 * k) {
#pragma unroll
        for (int i = 0; i < k; ++i) {
          int a = j + i, b = j + i + k;
          if (b < 16 && (a / (2 * p)) == (b / (2 * p))) {
            u64 hi = s[a] > s[b] ? s[a] : s[b];
            u64 lo = s[a] > s[b] ? s[b] : s[a];
            s[a] = hi;
            s[b] = lo;
          }
        }
      }
    }
  }
#pragma unroll
  for (int r = 0; r < KNN; ++r) {
    u64 win = s[0];
#pragma unroll
    for (int off = 32; off > 0; off >>= 1) {
      u64 o = __shfl_xor(win, off, 64);
      win = o > win ? o : win;
    }
    if (lane == 0) op[r] = 1023 - (int)(win & (u64)1023);
    if (s[0] == win) {
#pragma unroll
      for (int i = 0; i < 15; ++i) s[i] = s[i + 1];
      s[15] = 0ULL;
    }
  }
}

// ======== f64 MFMA layout self-probe + decode, fused (one wave, ~3us) ========
// P1: A=lane&15, B=1   -> D[i][j] = 4*i  (A-side row class per (lane,reg))
// P2: A=1, B=lane&15   -> D[i][j] = 4*j  (B-side col class)
// P3: A=3^(lane>>4), B=5^(lane>>4) -> sum_k 15^k = 3616 (channel pairing)
// Each lane validates its 4 entries; bijectivity via 256-slot LDS histogram.
__global__ void k_probe_mfma(int* __restrict__ rowt, int* __restrict__ colt,
                             int* __restrict__ flag) {
  __shared__ int cnt[256];
  __shared__ int oksh;
  int tid = threadIdx.x;  // 64 threads
  if (tid == 0) oksh = 1;
  for (int e = tid; e < 256; e += 64) cnt[e] = 0;
  __syncthreads();
  int lane = tid & 63;
  f64x4 z = {0.0, 0.0, 0.0, 0.0};
  double ai = (double)(lane & 15);
  double p3 = 1.0, p5 = 1.0;
  int kq = lane >> 4;
  for (int t = 0; t < kq; ++t) { p3 *= 3.0; p5 *= 5.0; }
  f64x4 d1 = __builtin_amdgcn_mfma_f64_16x16x4f64(ai, 1.0, z, 0, 0, 0);
  f64x4 d2 = __builtin_amdgcn_mfma_f64_16x16x4f64(1.0, ai, z, 0, 0, 0);
  f64x4 d3 = __builtin_amdgcn_mfma_f64_16x16x4f64(p3, p5, z, 0, 0, 0);
  bool ok = true;
  int ri[4], ci[4];
#pragma unroll
  for (int r = 0; r < 4; ++r) {
    double va = d1[r], vb = d2[r], vp = d3[r];
    int i = (int)(va * 0.25);
    int j = (int)(vb * 0.25);
    bool e_ok = (i >= 0) && (i < 16) && (j >= 0) && (j < 16) &&
                (va == 4.0 * (double)i) && (vb == 4.0 * (double)j) && (vp == 3616.0);
    if (e_ok) {
      atomicAdd(&cnt[i * 16 + j], 1);
    } else {
      ok = false;
      i = 0;
      j = 0;
    }
    ri[r] = i;
    ci[r] = j;
  }
  if (!ok) atomicExch(&oksh, 0);
  __syncthreads();
  bool bij = true;
  for (int e = tid; e < 256; e += 64)
    if (cnt[e] != 1) bij = false;
  if (!bij) atomicExch(&oksh, 0);
  __syncthreads();
#pragma unroll
  for (int r = 0; r < 4; ++r) {
    rowt[lane * 4 + r] = ri[r];
    colt[lane * 4 + r] = ci[r];
  }
  if (tid == 0) *flag = oksh;
}

// ---------------- transpose f32 -> f64: (B,C,Np) -> (B,Np,C) ----------------
__global__ __launch_bounds__(256) void k_transpose_d(
    const float* __restrict__ in, double* __restrict__ out, int C, int Np) {
  int total = BB * C * Np;
  for (int t = blockIdx.x * 256 + threadIdx.x; t < total; t += gridDim.x * 256) {
    int c = t % C;
    int n = (t / C) % Np;
    int b = t / (C * Np);
    out[t] = (double)in[((size_t)b * C + c) * Np + n];
  }
}

// ---------------- f32 -> bf16 convert ----------------
__global__ __launch_bounds__(256) void k_cvt_bf16(
    const float* __restrict__ in, __hip_bfloat16* __restrict__ out, int n) {
  int i = blockIdx.x * 256 + threadIdx.x;
  if (i < n) out[i] = __float2bfloat16(in[i]);
}

// ------- per-point squared norm (RECIP=0) or reciprocal norm (RECIP=1), f64 -------
template <int RECIP>
__global__ __launch_bounds__(256) void k_rowsq(
    const double* __restrict__ A, int ld, int C, double* __restrict__ sq) {
  int p = blockIdx.x * 256 + threadIdx.x;
  if (p >= BB * NN) return;
  const double* row = A + (size_t)p * ld;
  double s = 0.0;
  for (int c = 0; c < C; ++c) { double v = row[c]; s += v * v; }
  if (RECIP) {
    sq[p] = 1.0 / fmax(sqrt(s), 1e-12);
  } else {
    sq[p] = s;
  }
}

// ---- fused L1 knn (C=3): all points in LDS (f64), u64-key topk (exact) ----
__global__ __launch_bounds__(256) void k_knn3(
    const double* __restrict__ xs3, const double* __restrict__ sq, int* __restrict__ idx) {
  __shared__ double P[NN * 3];
  int b = blockIdx.x;
  const double* Xb = xs3 + (size_t)b * NN * 3;
  int tid = threadIdx.x;
  for (int t = tid; t < NN * 3; t += 256) P[t] = Xb[t];
  __syncthreads();
  int wave = tid >> 6, lane = tid & 63;
  int i = blockIdx.y * 4 + wave;
  double xi = P[i * 3], yi = P[i * 3 + 1], zi = P[i * 3 + 2];
  double sqi = sq[b * NN + i];
  u64 s[16];
#pragma unroll
  for (int m = 0; m < 16; ++m) {
    int j = m * 64 + lane;
    double d = fma(xi, P[j * 3], 0.0);
    d = fma(yi, P[j * 3 + 1], d);
    d = fma(zi, P[j * 3 + 2], d);
    s[m] = pack_key64(2.0 * d - sqi - sq[b * NN + j], j);
  }
  int* op = idx + ((size_t)b * NN + i) * KNN;
  topk20_u64(s, lane, op);
}

// ---- unified gram: 64x64 tile / WG. If *flag: f64 MFMA path with probe-decoded
// D tables (robust to any D permutation). Else: verified VALU-FMA path.
// Writes exact u64 keys ONLY. MODE 1: D = 2*dot - sqA_i - sqB_j ; MODE 2: dot*rnA*rnB
template <int MODE>
__global__ __launch_bounds__(256) void k_gram_u(
    const double* __restrict__ A, int lda, const double* __restrict__ Bm, int ldb,
    const double* __restrict__ sqA, const double* __restrict__ sqB,
    u64* __restrict__ kk, int C, int b0, const int* __restrict__ rowt,
    const int* __restrict__ colt, const int* __restrict__ flag) {
  __shared__ double As[16][66];
  __shared__ double Bs[16][66];
  int bg = b0 + blockIdx.x;
  int bl = blockIdx.x;
  int j0 = blockIdx.y * 64;
  int i0 = blockIdx.z * 64;
  const double* Ab = A + (size_t)bg * NN * lda;
  const double* Bb = Bm + (size_t)bg * MM * ldb;
  int tid = threadIdx.x;
  if (*flag) {
    int lane = tid & 63, w = tid >> 6;
    int lm = lane & 15, lq = lane >> 4;
    f64x4 acc[4] = {};
    for (int c0 = 0; c0 < C; c0 += 16) {
      if (c0) __syncthreads();
      for (int r = 0; r < 4; ++r) {
        int li = tid + r * 256;
        int row = li >> 4, k = li & 15;
        As[k][row] = Ab[(size_t)(i0 + row) * lda + c0 + k];
        Bs[k][row] = Bb[(size_t)(j0 + row) * ldb + c0 + k];
      }
      __syncthreads();
#pragma unroll
      for (int kc = 0; kc < 4; ++kc) {
        double a = As[kc * 4 + lq][w * 16 + lm];
#pragma unroll
        for (int t = 0; t < 4; ++t) {
          double b = Bs[kc * 4 + lq][t * 16 + lm];
          acc[t] = __builtin_amdgcn_mfma_f64_16x16x4f64(a, b, acc[t], 0, 0, 0);
        }
      }
    }
    int rta[4], cta[4];
#pragma unroll
    for (int r = 0; r < 4; ++r) {
      rta[r] = rowt[lane * 4 + r];
      cta[r] = colt[lane * 4 + r];
    }
#pragma unroll
    for (int t = 0; t < 4; ++t) {
#pragma unroll
      for (int r = 0; r < 4; ++r) {
        int i = i0 + w * 16 + rta[r];
        int j = j0 + t * 16 + cta[r];
        double v = acc[t][r];
        if (MODE == 1) v = 2.0 * v - sqA[(size_t)bg * NN + i] - sqB[(size_t)bg * MM + j];
        if (MODE == 2) v = v * sqA[(size_t)bg * NN + i] * sqB[(size_t)bg * MM + j];
        kk[((size_t)bl * NN + i) * MM + j] = pack_key64(v, j);
      }
    }
  } else {
    int tx = tid & 15, ty = tid >> 4;
    double acc[4][4] = {};
    for (int c0 = 0; c0 < C; c0 += 16) {
      if (c0) __syncthreads();
      for (int r = 0; r < 4; ++r) {
        int li = tid + r * 256;
        int row = li >> 4, k = li & 15;
        As[k][row] = Ab[(size_t)(i0 + row) * lda + c0 + k];
        Bs[k][row] = Bb[(size_t)(j0 + row) * ldb + c0 + k];
      }
      __syncthreads();
#pragma unroll
      for (int k = 0; k < 16; ++k) {
        double a_[4], b_[4];
#pragma unroll
        for (int ii = 0; ii < 4; ++ii) a_[ii] = As[k][ty * 4 + ii];
#pragma unroll
        for (int jj = 0; jj < 4; ++jj) b_[jj] = Bs[k][jj * 16 + tx];
#pragma unroll
        for (int ii = 0; ii < 4; ++ii)
#pragma unroll
          for (int jj = 0; jj < 4; ++jj)
            acc[ii][jj] = fma(a_[ii], b_[jj], acc[ii][jj]);
      }
    }
    for (int ii = 0; ii < 4; ++ii) {
      int i = i0 + ty * 4 + ii;
      double qa = sqA[(size_t)bg * NN + i];
      for (int jj = 0; jj < 4; ++jj) {
        int j = j0 + jj * 16 + tx;
        double v = acc[ii][jj];
        if (MODE == 1) v = 2.0 * v - qa - sqB[(size_t)bg * MM + j];
        if (MODE == 2) v = v * qa * sqB[(size_t)bg * MM + j];
        kk[((size_t)bl * NN + i) * MM + j] = pack_key64(v, j);
      }
    }
  }
}

// ------- top-20 per row from exact u64 keys; no fallback -------
__global__ __launch_bounds__(256) void k_topk(const u64* __restrict__ kk,
                                              int* __restrict__ idx, int b0) {
  int wave = threadIdx.x >> 6;
  int lane = threadIdx.x & 63;
  int bl = blockIdx.x;
  int row = blockIdx.y * 4 + wave;
  const u64* rp = kk + ((size_t)bl * NN + row) * MM;
  u64 s[16];
#pragma unroll
  for (int m = 0; m < 16; ++m) s[m] = rp[m * 64 + lane];
  int* op = idx + ((size_t)(b0 + bl) * NN + row) * KNN;
  topk20_u64(s, lane, op);
}

// --- fused per-point feature matmul (f64), both modes in one launch ---
// mode 0: out0[b,j,o] = sum_c src0[b,j,c]*w[o,c]
// mode 1: out1[b,j,o] = sum_c src1[b,j,c]*(w[o,C+c]-w[o,c])
__global__ __launch_bounds__(256) void k_featmm2(
    const double* __restrict__ src0, int ld0, int Np0,
    const double* __restrict__ src1, int ld1,
    const float* __restrict__ w, int CW,
    double* __restrict__ out0, double* __restrict__ out1, int C, int O) {
  __shared__ double As[16][68];
  __shared__ double Ws[16][68];
  int nbo = O >> 6;
  int b = blockIdx.x;
  int mode = blockIdx.y >= nbo;
  int o0 = (blockIdx.y - (mode ? nbo : 0)) * 64;
  int j0 = blockIdx.z * 64;
  const double* src = mode ? src1 : src0;
  int lds_ = mode ? ld1 : ld0;
  int Np = mode ? NN : Np0;
  double* out = mode ? out1 : out0;
  int tx = threadIdx.x, ty = threadIdx.y;
  int tid = ty * 16 + tx;
  const double* Sb = src + (size_t)b * Np * lds_;
  double acc[4][4] = {};
  for (int c0 = 0; c0 < C; c0 += 16) {
    for (int r = 0; r < 4; ++r) {
      int li = tid + r * 256;
      int row = li >> 4, k = li & 15;
      int c = c0 + k;
      As[k][row] = (c < C) ? Sb[(size_t)(j0 + row) * lds_ + c] : 0.0;
      double wv = 0.0;
      if (c < C) {
        const float* wr = w + (size_t)(o0 + row) * CW;
        wv = (mode == 0) ? (double)wr[c] : ((double)wr[C + c] - (double)wr[c]);
      }
      Ws[k][row] = wv;
    }
    __syncthreads();
#pragma unroll
    for (int k = 0; k < 16; ++k) {
      double a_[4], b_[4];
#pragma unroll
      for (int ii = 0; ii < 4; ++ii) a_[ii] = As[k][ty * 4 + ii];
#pragma unroll
      for (int jj = 0; jj < 4; ++jj) b_[jj] = Ws[k][tx * 4 + jj];
#pragma unroll
      for (int ii = 0; ii < 4; ++ii)
#pragma unroll
        for (int jj = 0; jj < 4; ++jj)
          acc[ii][jj] = fma(a_[ii], b_[jj], acc[ii][jj]);
    }
    __syncthreads();
  }
  for (int ii = 0; ii < 4; ++ii) {
    int j = j0 + ty * 4 + ii;
    double* op = &out[((size_t)b * Np + j) * O + o0 + tx * 4];
    double2 v0, v1;
    v0.x = acc[ii][0];
    v0.y = acc[ii][1];
    v1.x = acc[ii][2];
    v1.y = acc[ii][3];
    *(double2*)op = v0;
    *(double2*)(op + 2) = v1;
  }
}

// ---- layer-5 GEMM via bf16 MFMA: per-wave 16x16 tile, frags direct from global ----
__global__ __launch_bounds__(256) void k_gemm5_mfma(
    const __hip_bfloat16* __restrict__ cath, const __hip_bfloat16* __restrict__ w5h,
    float* __restrict__ out) {
  int b = blockIdx.x;
  int j0 = blockIdx.y * 16;
  int o0 = blockIdx.z * 64 + (threadIdx.x >> 6) * 16;
  int lane = threadIdx.x & 63;
  int m = lane & 15;
  int quad = lane >> 4;
  const __hip_bfloat16* arow = cath + ((size_t)b * NN + j0 + m) * 512 + quad * 8;
  const __hip_bfloat16* brow = w5h + (size_t)(o0 + m) * 512 + quad * 8;
  f32x4 acc = {0.f, 0.f, 0.f, 0.f};
#pragma unroll
  for (int c0 = 0; c0 < 512; c0 += 32) {
    bf16x8 a = *(const bf16x8*)(arow + c0);
    bf16x8 bb = *(const bf16x8*)(brow + c0);
    acc = __builtin_amdgcn_mfma_f32_16x16x32_bf16(a, bb, acc, 0, 0, 0);
  }
  float* obase = &out[((size_t)b * NN + j0 + quad * 4) * 512 + o0 + m];
#pragma unroll
  for (int r = 0; r < 4; ++r) obase[(size_t)r * 512] = acc[r];
}

// ------- fused gather (f64): per (n,o) max_k y, accumulate BN stats -------
__global__ __launch_bounds__(256) void k_gather(
    const double* __restrict__ u, const double* __restrict__ t, const int* __restrict__ idx,
    double* __restrict__ stats, double* __restrict__ mx, int O, int srcNp) {
  __shared__ int lidx[16 * KNN];
  __shared__ double rs[256];
  __shared__ double rq[256];
  int b = blockIdx.x;
  int n0 = blockIdx.y * 16;
  int o0 = blockIdx.z * 64;
  int tid = threadIdx.x;
  int lane = tid & 63, nsl = tid >> 6;
  for (int w = tid; w < 16 * KNN; w += 256)
    lidx[w] = idx[((size_t)b * NN + n0) * KNN + w];
  __syncthreads();
  int oo = o0 + lane;
  double s1 = 0.0, s2 = 0.0;
  for (int ns = nsl; ns < 16; ns += 4) {
    size_t row = (size_t)b * NN + n0 + ns;
    double tv = t[row * O + oo];
    double mxv = -INFINITY;
    double a1 = 0.0, a2 = 0.0;
#pragma unroll
    for (int k = 0; k < KNN; ++k) {
      int j = lidx[ns * KNN + k];
      double yv = u[((size_t)b * srcNp + j) * O + oo] + tv;
      mxv = fmax(mxv, yv);
      a1 += yv;
      a2 = fma(yv, yv, a2);
    }
    mx[row * O + oo] = mxv;
    s1 += a1;
    s2 += a2;
  }
  rs[tid] = s1;
  rq[tid] = s2;
  __syncthreads();
  if (tid < 64) {
    s1 = rs[tid] + rs[tid + 64] + rs[tid + 128] + rs[tid + 192];
    s2 = rq[tid] + rq[tid + 64] + rq[tid + 128] + rq[tid + 192];
    atomicAdd(&stats[o0 + tid], s1);
    atomicAdd(&stats[O + o0 + tid], s2);
  }
}

// ---------------- fold BN into per-channel scale/shift (f64) ----------------
__global__ void k_bnfin(const double* __restrict__ stats, const float* __restrict__ gamma,
                        const float* __restrict__ beta, double* __restrict__ sc,
                        int O, double cnt) {
  int o = threadIdx.x;
  if (o >= O) return;
  double mean = stats[o] / cnt;
  double var = stats[O + o] / cnt - mean * mean;
  if (var < 0.0) var = 0.0;
  double rstd = 1.0 / sqrt(var + 1e-5);
  double s = (double)gamma[o] * rstd;
  double c = (double)beta[o] - mean * s;
  sc[o] = s;
  sc[O + o] = c;
}

// --- apply BN+lrelu to stored max (f64); write catd (f64, knn channels) + bf16 ---
__global__ __launch_bounds__(256) void k_bnapply(
    const double* __restrict__ mx, const double* __restrict__ u, const double* __restrict__ t,
    const int* __restrict__ idx, const double* __restrict__ sc, double* __restrict__ catd,
    __hip_bfloat16* __restrict__ cath, int coff, int O, int srcNp) {
  int i = blockIdx.x * 256 + threadIdx.x;
  int total = BB * NN * O;
  if (i >= total) return;
  int oo = i % O;
  int n = (i / O) % NN;
  int b = i / (O * NN);
  double s = sc[oo], c = sc[O + oo];
  double v;
  if (s >= 0.0) {
    v = mx[i];
  } else {  // monotone-decreasing transform needs min_k y (never hit with gamma=1)
    double tv = t[i];
    double mn = INFINITY;
    for (int k = 0; k < KNN; ++k) {
      int j = idx[((size_t)b * NN + n) * KNN + k];
      mn = fmin(mn, u[((size_t)b * srcNp + j) * O + oo] + tv);
    }
    v = mn;
  }
  double a = s * v + c;
  a = (a >= 0.0) ? a : 0.2 * a;
  size_t ci = ((size_t)b * NN + n) * 512 + coff + oo;
  cath[ci] = __float2bfloat16((float)a);
  if (coff < 256) catd[((size_t)b * NN + n) * 256 + coff + oo] = a;
}

// ------- layer 5 streaming stats over stored y5 (B,N,512) -------
__global__ __launch_bounds__(256) void k_stats512(
    const float* __restrict__ y5, double* __restrict__ stats) {
  int b = blockIdx.y;
  int n0 = blockIdx.x * 32;
  int tid = threadIdx.x;
  for (int part = 0; part < 2; ++part) {
    int oo = tid + part * 256;
    float a1 = 0.f, a2 = 0.f;
    for (int ns = 0; ns < 32; ++ns) {
      float v = y5[((size_t)b * NN + n0 + ns) * 512 + oo];
      a1 += v;
      a2 = fmaf(v, v, a2);
    }
    atomicAdd(&stats[oo], (double)a1);
    atomicAdd(&stats[512 + oo], (double)a2);
  }
}

// ------- layer 5 finalize: BN+lrelu on stored y5, transpose, f32 store -------
__global__ __launch_bounds__(256) void k_final5b(
    const float* __restrict__ y5, const double* __restrict__ sc, float* __restrict__ out) {
  __shared__ float tile[64][65];
  int b = blockIdx.z;
  int n0 = blockIdx.x * 64;
  int o0 = blockIdx.y * 64;
  int tid = threadIdx.x;
  for (int r = 0; r < 16; ++r) {
    int li = tid + r * 256;
    int nl = li >> 6, ol = li & 63;
    float v = y5[((size_t)b * NN + n0 + nl) * 512 + o0 + ol];
    float a = (float)(sc[o0 + ol] * (double)v + sc[512 + o0 + ol]);
    a = (a >= 0.f) ? a : NEG_SLOPE * a;
    tile[nl][ol] = a;
  }
  __syncthreads();
  for (int r = 0; r < 16; ++r) {
    int li = tid + r * 256;
    int ol = li >> 6, nl = li & 63;
    out[((size_t)b * 512 + o0 + ol) * NN + n0 + nl] = tile[nl][ol];
  }
}

// =====================================================================================
// r18: r17's top dispatch was k_probe_decode <<<1,1>>> at 104us (13% of total!) --
// one thread, 256 serial dependent global loads, pure latency. Fix: probe+decode
// fused into ONE 64-thread kernel; per-lane arithmetic validation, bijectivity via
// 256-slot LDS histogram (atomicAdd + parallel scan). ~3us. Everything else
// unchanged (u64-key exact topk + probe-gated MFMA/FMA dual gram, verified r17).
extern "C" void kernel_launch(void* const* d_in, const int* in_sizes, int n_in,
                              void* d_out, int out_size, void* d_ws, size_t ws_size,
                              hipStream_t stream) {
  const float* x = (const float*)d_in[0];
  const float* y = (const float*)d_in[1];
  const float* w1 = (const float*)d_in[2];
  const float* w2 = (const float*)d_in[3];
  const float* w3 = (const float*)d_in[4];
  const float* w4 = (const float*)d_in[5];
  const float* w5 = (const float*)d_in[6];
  const float* g1 = (const float*)d_in[7];
  const float* b1 = (const float*)d_in[8];
  const float* g2 = (const float*)d_in[9];
  const float* b2 = (const float*)d_in[10];
  const float* g3 = (const float*)d_in[11];
  const float* b3 = (const float*)d_in[12];
  const float* g4 = (const float*)d_in[13];
  const float* b4 = (const float*)d_in[14];
  const float* g5 = (const float*)d_in[15];
  const float* b5 = (const float*)d_in[16];

  char* base = (char*)d_ws;
  size_t off = 0;
  auto alloc = [&](size_t bytes) -> char* {
    char* p = base + off;
    off += (bytes + 255) & ~(size_t)255;
    return p;
  };
  double* st = (double*)alloc(1024 * 8);
  double* sc = (double*)alloc(1024 * 8);
  double* sq = (double*)alloc((size_t)BB * NN * 8);
  double* rnx = (double*)alloc((size_t)BB * NN * 8);
  double* rny = (double*)alloc((size_t)BB * MM * 8);
  int* idxb = (int*)alloc((size_t)BB * NN * KNN * 4);
  int* rowt = (int*)alloc(256 * 4);
  int* colt = (int*)alloc(256 * 4);
  int* pflag = (int*)alloc(256);
  double* xs3d = (double*)alloc((size_t)BB * NN * 3 * 8);
  double* ysd = (double*)alloc((size_t)BB * MM * 128 * 8);
  double* catd = (double*)alloc((size_t)BB * NN * 256 * 8);  // knn channels 0..255
  __hip_bfloat16* cath = (__hip_bfloat16*)alloc((size_t)BB * NN * 512 * 2);
  __hip_bfloat16* w5h = (__hip_bfloat16*)alloc((size_t)512 * 512 * 2);
  double* uu = (double*)alloc((size_t)BB * MM * 256 * 8);  // src term (max O=256)
  double* tt = (double*)alloc((size_t)BB * NN * 256 * 8);  // center term
  size_t kkBatchBytes = (size_t)NN * MM * 8;  // 8 MB per batch (u64 keys)
  size_t avail = (ws_size > off) ? (ws_size - off) : 0;
  int CB = (int)(avail / kkBatchBytes);
  if (CB < 1) CB = 1;
  if (CB > BB) CB = BB;
  u64* KK = (u64*)alloc((size_t)CB * kkBatchBytes);
  float* y5 = (float*)uu;             // layer-5 pre-BN (16MB), uu dead by then
  double* mx = (double*)d_out;        // max_k y (f64, <=16MB == out_size)
  float* outp = (float*)d_out;

  const dim3 blk2(16, 16);
  const double cntE = (double)BB * NN * KNN;

  auto knn = [&](const double* A, int lda, const double* Bm, int ldb,
                 const double* sa, const double* sb, int C, int mode) {
    for (int b0 = 0; b0 < BB; b0 += CB) {
      int cb = (BB - b0 < CB) ? (BB - b0) : CB;
      dim3 g(cb, MM / 64, NN / 64);
      if (mode == 1)
        k_gram_u<1><<<g, 256, 0, stream>>>(A, lda, Bm, ldb, sa, sb, KK, C, b0, rowt,
                                           colt, pflag);
      else
        k_gram_u<2><<<g, 256, 0, stream>>>(A, lda, Bm, ldb, sa, sb, KK, C, b0, rowt,
                                           colt, pflag);
      k_topk<<<dim3(cb, 256), 256, 0, stream>>>(KK, idxb, b0);
    }
  };

  auto edge_layer = [&](const double* ctr, int ldc, const double* src, int ldsrc,
                        int srcNp, const float* w, int CW, const float* g,
                        const float* bb, int C, int O, int coff) {
    k_featmm2<<<dim3(8, 2 * (O / 64), 16), blk2, 0, stream>>>(src, ldsrc, srcNp, ctr,
                                                              ldc, w, CW, uu, tt, C, O);
    hipMemsetAsync(st, 0, 1024 * 8, stream);
    k_gather<<<dim3(BB, NN / 16, O / 64), 256, 0, stream>>>(uu, tt, idxb, st, mx, O,
                                                            srcNp);
    k_bnfin<<<1, O, 0, stream>>>(st, g, bb, sc, O, cntE);
    k_bnapply<<<(BB * NN * O + 255) / 256, 256, 0, stream>>>(mx, uu, tt, idxb, sc, catd,
                                                             cath, coff, O, srcNp);
  };

  // ---- f64-MFMA layout probe (fused decode) + input transposes + w5 bf16 ----
  k_probe_mfma<<<1, 64, 0, stream>>>(rowt, colt, pflag);
  k_transpose_d<<<96, 256, 0, stream>>>(x, xs3d, 3, NN);
  k_transpose_d<<<2048, 256, 0, stream>>>(y, ysd, 128, MM);
  k_cvt_bf16<<<1024, 256, 0, stream>>>(w5, w5h, 512 * 512);

  // ---- layer 1: C=3, O=64 (fused knn, no gram) ----
  k_rowsq<0><<<32, 256, 0, stream>>>(xs3d, 3, 3, sq);
  k_knn3<<<dim3(BB, 256), 256, 0, stream>>>(xs3d, sq, idxb);
  edge_layer(xs3d, 3, xs3d, 3, NN, w1, 6, g1, b1, 3, 64, 0);

  // ---- layer 2: x1 = catd[:,0:64], C=64, O=64 ----
  k_rowsq<0><<<32, 256, 0, stream>>>(catd, 256, 64, sq);
  knn(catd, 256, catd, 256, sq, sq, 64, 1);
  edge_layer(catd, 256, catd, 256, NN, w2, 128, g2, b2, 64, 64, 64);

  // ---- layer 3: x2 = catd[:,64:128], C=64, O=128 ----
  k_rowsq<0><<<32, 256, 0, stream>>>(catd + 64, 256, 64, sq);
  knn(catd + 64, 256, catd + 64, 256, sq, sq, 64, 1);
  edge_layer(catd + 64, 256, catd + 64, 256, NN, w3, 128, g3, b3, 64, 128, 128);

  // ---- layer 4 (IA): x3 = catd[:,128:256], src = y (cosine knn), C=128, O=256 ----
  k_rowsq<1><<<32, 256, 0, stream>>>(catd + 128, 256, 128, rnx);
  k_rowsq<1><<<32, 256, 0, stream>>>(ysd, 128, 128, rny);
  knn(catd + 128, 256, ysd, 128, rnx, rny, 128, 2);
  edge_layer(catd + 128, 256, ysd, 128, MM, w4, 256, g4, b4, 128, 256, 256);

  // ---- layer 5: bf16-MFMA GEMM -> y5 (aliases uu), BN over (B,N), lrelu, transpose ----
  hipMemsetAsync(st, 0, 1024 * 8, stream);
  k_gemm5_mfma<<<dim3(BB, 64, 8), 256, 0, stream>>>(cath, w5h, y5);
  k_stats512<<<dim3(32, 8), 256, 0, stream>>>(y5, st);
  k_bnfin<<<1, 512, 0, stream>>>(st, g5, b5, sc, 512, (double)(BB * NN));
  k_final5b<<<dim3(16, 8, 8), 256, 0, stream>>>(y5, sc, outp);
}

// Round 6
// 708.734 us; speedup vs baseline: 1.4321x; 1.0217x over previous
//
#include <hip/hip_runtime.h>
#include <hip/hip_bf16.h>

#define KNN 20
#define NEG_SLOPE 0.2f

constexpr int BB = 8;
constexpr int NN = 1024;
constexpr int MM = 1024;

typedef short bf16x8 __attribute__((ext_vector_type(8)));
typedef float f32x4 __attribute__((ext_vector_type(4)));
typedef double f64x4 __attribute__((ext_vector_type(4)));
typedef unsigned long long u64;

// ================= top-20 selection via exact u64 keys =================
// Monotone f64->u64 map, low 10 bits replaced by inverted column index.
// Key order == f64 descending order with tie -> lower idx (jax top_k semantics),
// up to 2^-43 relative granularity (far below the f64-pipeline noise floor).
__device__ __forceinline__ u64 pack_key64(double d, int j) {
  u64 u = (u64)__double_as_longlong(d);
  u = (u & 0x8000000000000000ULL) ? ~u : (u | 0x8000000000000000ULL);
  return (u & ~(u64)1023) | (u64)(1023 - j);
}

// Per-wave top-20: each lane holds 16 keys; Batcher odd-even mergesort (desc),
// then 20 extraction rounds (wave-max + winner-lane shift). Exact, no fallback.
__device__ __forceinline__ void topk20_u64(u64 (&s)[16], int lane, int* op) {
#pragma unroll
  for (int p = 1; p < 16; p <<= 1) {
#pragma unroll
    for (int k = p; k >= 1; k >>= 1) {
#pragma unroll
      for (int j = k % p; j + k < 16; j += 2 * k) {
#pragma unroll
        for (int i = 0; i < k; ++i) {
          int a = j + i, b = j + i + k;
          if (b < 16 && (a / (2 * p)) == (b / (2 * p))) {
            u64 hi = s[a] > s[b] ? s[a] : s[b];
            u64 lo = s[a] > s[b] ? s[b] : s[a];
            s[a] = hi;
            s[b] = lo;
          }
        }
      }
    }
  }
#pragma unroll
  for (int r = 0; r < KNN; ++r) {
    u64 win = s[0];
#pragma unroll
    for (int off = 32; off > 0; off >>= 1) {
      u64 o = __shfl_xor(win, off, 64);
      win = o > win ? o : win;
    }
    if (lane == 0) op[r] = 1023 - (int)(win & (u64)1023);
    if (s[0] == win) {
#pragma unroll
      for (int i = 0; i < 15; ++i) s[i] = s[i + 1];
      s[15] = 0ULL;
    }
  }
}

// ======== f64 MFMA layout self-probe + decode, fused (one wave, ~3us) ========
// P1: A=lane&15, B=1   -> D[i][j] = 4*i  (A-side row class per (lane,reg))
// P2: A=1, B=lane&15   -> D[i][j] = 4*j  (B-side col class)
// P3: A=3^(lane>>4), B=5^(lane>>4) -> sum_k 15^k = 3616 (channel pairing)
// Each lane validates its 4 entries; bijectivity via 256-slot LDS histogram.
__global__ void k_probe_mfma(int* __restrict__ rowt, int* __restrict__ colt,
                             int* __restrict__ flag) {
  __shared__ int cnt[256];
  __shared__ int oksh;
  int tid = threadIdx.x;  // 64 threads
  if (tid == 0) oksh = 1;
  for (int e = tid; e < 256; e += 64) cnt[e] = 0;
  __syncthreads();
  int lane = tid & 63;
  f64x4 z = {0.0, 0.0, 0.0, 0.0};
  double ai = (double)(lane & 15);
  double p3 = 1.0, p5 = 1.0;
  int kq = lane >> 4;
  for (int t = 0; t < kq; ++t) { p3 *= 3.0; p5 *= 5.0; }
  f64x4 d1 = __builtin_amdgcn_mfma_f64_16x16x4f64(ai, 1.0, z, 0, 0, 0);
  f64x4 d2 = __builtin_amdgcn_mfma_f64_16x16x4f64(1.0, ai, z, 0, 0, 0);
  f64x4 d3 = __builtin_amdgcn_mfma_f64_16x16x4f64(p3, p5, z, 0, 0, 0);
  bool ok = true;
  int ri[4], ci[4];
#pragma unroll
  for (int r = 0; r < 4; ++r) {
    double va = d1[r], vb = d2[r], vp = d3[r];
    int i = (int)(va * 0.25);
    int j = (int)(vb * 0.25);
    bool e_ok = (i >= 0) && (i < 16) && (j >= 0) && (j < 16) &&
                (va == 4.0 * (double)i) && (vb == 4.0 * (double)j) && (vp == 3616.0);
    if (e_ok) {
      atomicAdd(&cnt[i * 16 + j], 1);
    } else {
      ok = false;
      i = 0;
      j = 0;
    }
    ri[r] = i;
    ci[r] = j;
  }
  if (!ok) atomicExch(&oksh, 0);
  __syncthreads();
  bool bij = true;
  for (int e = tid; e < 256; e += 64)
    if (cnt[e] != 1) bij = false;
  if (!bij) atomicExch(&oksh, 0);
  __syncthreads();
#pragma unroll
  for (int r = 0; r < 4; ++r) {
    rowt[lane * 4 + r] = ri[r];
    colt[lane * 4 + r] = ci[r];
  }
  if (tid == 0) *flag = oksh;
}

// ---------------- transpose f32 -> f64: (B,C,Np) -> (B,Np,C) ----------------
__global__ __launch_bounds__(256) void k_transpose_d(
    const float* __restrict__ in, double* __restrict__ out, int C, int Np) {
  int total = BB * C * Np;
  for (int t = blockIdx.x * 256 + threadIdx.x; t < total; t += gridDim.x * 256) {
    int c = t % C;
    int n = (t / C) % Np;
    int b = t / (C * Np);
    out[t] = (double)in[((size_t)b * C + c) * Np + n];
  }
}

// ---------------- f32 -> bf16 convert ----------------
__global__ __launch_bounds__(256) void k_cvt_bf16(
    const float* __restrict__ in, __hip_bfloat16* __restrict__ out, int n) {
  int i = blockIdx.x * 256 + threadIdx.x;
  if (i < n) out[i] = __float2bfloat16(in[i]);
}

// ------- per-point squared norm (RECIP=0) or reciprocal norm (RECIP=1), f64 -------
template <int RECIP>
__global__ __launch_bounds__(256) void k_rowsq(
    const double* __restrict__ A, int ld, int C, double* __restrict__ sq) {
  int p = blockIdx.x * 256 + threadIdx.x;
  if (p >= BB * NN) return;
  const double* row = A + (size_t)p * ld;
  double s = 0.0;
  for (int c = 0; c < C; ++c) { double v = row[c]; s += v * v; }
  if (RECIP) {
    sq[p] = 1.0 / fmax(sqrt(s), 1e-12);
  } else {
    sq[p] = s;
  }
}

// ---- fused L1 knn (C=3): all points in LDS (f64), u64-key topk (exact) ----
__global__ __launch_bounds__(256) void k_knn3(
    const double* __restrict__ xs3, const double* __restrict__ sq, int* __restrict__ idx) {
  __shared__ double P[NN * 3];
  int b = blockIdx.x;
  const double* Xb = xs3 + (size_t)b * NN * 3;
  int tid = threadIdx.x;
  for (int t = tid; t < NN * 3; t += 256) P[t] = Xb[t];
  __syncthreads();
  int wave = tid >> 6, lane = tid & 63;
  int i = blockIdx.y * 4 + wave;
  double xi = P[i * 3], yi = P[i * 3 + 1], zi = P[i * 3 + 2];
  double sqi = sq[b * NN + i];
  u64 s[16];
#pragma unroll
  for (int m = 0; m < 16; ++m) {
    int j = m * 64 + lane;
    double d = fma(xi, P[j * 3], 0.0);
    d = fma(yi, P[j * 3 + 1], d);
    d = fma(zi, P[j * 3 + 2], d);
    s[m] = pack_key64(2.0 * d - sqi - sq[b * NN + j], j);
  }
  int* op = idx + ((size_t)b * NN + i) * KNN;
  topk20_u64(s, lane, op);
}

// ---- unified gram: 128(i)x64(j) tile / WG, 4 waves. MFMA path (if *flag):
// double-buffered reg-staged LDS, wave w owns i-subtiles {w*16, 64+w*16} x 4 j-subtiles
// = 32 MFMA per K-block, ONE barrier per block (prefetch loads overlap MFMA).
// Probe-decoded D tables make the epilogue robust to any D permutation.
// Fallback (!*flag): verified VALU-FMA 8x4/thread. Writes exact u64 keys ONLY.
// MODE 1: D = 2*dot - sqA_i - sqB_j ; MODE 2: D = dot * rnA_i * rnB_j
template <int MODE>
__global__ __launch_bounds__(256) void k_gram_u(
    const double* __restrict__ A, int lda, const double* __restrict__ Bm, int ldb,
    const double* __restrict__ sqA, const double* __restrict__ sqB,
    u64* __restrict__ kk, int C, int b0, const int* __restrict__ rowt,
    const int* __restrict__ colt, const int* __restrict__ flag) {
  __shared__ double As[2][16][132];
  __shared__ double Bs[2][16][68];
  int bg = b0 + blockIdx.x;
  int bl = blockIdx.x;
  int j0 = blockIdx.y * 64;
  int i0 = blockIdx.z * 128;
  const double* Ab = A + (size_t)bg * NN * lda;
  const double* Bb = Bm + (size_t)bg * MM * ldb;
  int tid = threadIdx.x;
  if (*flag) {
    int lane = tid & 63, w = tid >> 6;
    int lm = lane & 15, lq = lane >> 4;
    f64x4 acc[2][4] = {};
    // prologue: stage K-block 0 into buf 0
    for (int r = 0; r < 8; ++r) {
      int li = tid + r * 256;
      int row = li >> 4, k = li & 15;
      As[0][k][row] = Ab[(size_t)(i0 + row) * lda + k];
    }
    for (int r = 0; r < 4; ++r) {
      int li = tid + r * 256;
      int row = li >> 4, k = li & 15;
      Bs[0][k][row] = Bb[(size_t)(j0 + row) * ldb + k];
    }
    __syncthreads();
    int nblk = C >> 4;
    for (int cb = 0; cb < nblk; ++cb) {
      int buf = cb & 1;
      double ra[8], rb[4];
      bool pf = (cb + 1 < nblk);
      if (pf) {  // issue next block's global loads early (latency hides under MFMA)
        int c0 = (cb + 1) << 4;
        for (int r = 0; r < 8; ++r) {
          int li = tid + r * 256;
          int row = li >> 4, k = li & 15;
          ra[r] = Ab[(size_t)(i0 + row) * lda + c0 + k];
        }
        for (int r = 0; r < 4; ++r) {
          int li = tid + r * 256;
          int row = li >> 4, k = li & 15;
          rb[r] = Bb[(size_t)(j0 + row) * ldb + c0 + k];
        }
      }
#pragma unroll
      for (int kc = 0; kc < 4; ++kc) {
        double a0 = As[buf][kc * 4 + lq][w * 16 + lm];
        double a1 = As[buf][kc * 4 + lq][64 + w * 16 + lm];
#pragma unroll
        for (int t = 0; t < 4; ++t) {
          double b = Bs[buf][kc * 4 + lq][t * 16 + lm];
          acc[0][t] = __builtin_amdgcn_mfma_f64_16x16x4f64(a0, b, acc[0][t], 0, 0, 0);
          acc[1][t] = __builtin_amdgcn_mfma_f64_16x16x4f64(a1, b, acc[1][t], 0, 0, 0);
        }
      }
      if (pf) {  // write prefetched regs into the other buffer
        int nb = buf ^ 1;
        for (int r = 0; r < 8; ++r) {
          int li = tid + r * 256;
          int row = li >> 4, k = li & 15;
          As[nb][k][row] = ra[r];
        }
        for (int r = 0; r < 4; ++r) {
          int li = tid + r * 256;
          int row = li >> 4, k = li & 15;
          Bs[nb][k][row] = rb[r];
        }
      }
      __syncthreads();
    }
    int rta[4], cta[4];
#pragma unroll
    for (int r = 0; r < 4; ++r) {
      rta[r] = rowt[lane * 4 + r];
      cta[r] = colt[lane * 4 + r];
    }
#pragma unroll
    for (int g = 0; g < 2; ++g) {
#pragma unroll
      for (int t = 0; t < 4; ++t) {
#pragma unroll
        for (int r = 0; r < 4; ++r) {
          int i = i0 + g * 64 + w * 16 + rta[r];
          int j = j0 + t * 16 + cta[r];
          double v = acc[g][t][r];
          if (MODE == 1)
            v = 2.0 * v - sqA[(size_t)bg * NN + i] - sqB[(size_t)bg * MM + j];
          if (MODE == 2) v = v * sqA[(size_t)bg * NN + i] * sqB[(size_t)bg * MM + j];
          kk[((size_t)bl * NN + i) * MM + j] = pack_key64(v, j);
        }
      }
    }
  } else {
    int tx = tid & 15, ty = tid >> 4;
    double acc[8][4] = {};
    for (int c0 = 0; c0 < C; c0 += 16) {
      if (c0) __syncthreads();
      for (int r = 0; r < 8; ++r) {
        int li = tid + r * 256;
        int row = li >> 4, k = li & 15;
        As[0][k][row] = Ab[(size_t)(i0 + row) * lda + c0 + k];
      }
      for (int r = 0; r < 4; ++r) {
        int li = tid + r * 256;
        int row = li >> 4, k = li & 15;
        Bs[0][k][row] = Bb[(size_t)(j0 + row) * ldb + c0 + k];
      }
      __syncthreads();
#pragma unroll
      for (int k = 0; k < 16; ++k) {
        double a_[8], b_[4];
#pragma unroll
        for (int ii = 0; ii < 8; ++ii) a_[ii] = As[0][k][ty * 8 + ii];
#pragma unroll
        for (int jj = 0; jj < 4; ++jj) b_[jj] = Bs[0][k][jj * 16 + tx];
#pragma unroll
        for (int ii = 0; ii < 8; ++ii)
#pragma unroll
          for (int jj = 0; jj < 4; ++jj)
            acc[ii][jj] = fma(a_[ii], b_[jj], acc[ii][jj]);
      }
    }
    for (int ii = 0; ii < 8; ++ii) {
      int i = i0 + ty * 8 + ii;
      double qa = sqA[(size_t)bg * NN + i];
      for (int jj = 0; jj < 4; ++jj) {
        int j = j0 + jj * 16 + tx;
        double v = acc[ii][jj];
        if (MODE == 1) v = 2.0 * v - qa - sqB[(size_t)bg * MM + j];
        if (MODE == 2) v = v * qa * sqB[(size_t)bg * MM + j];
        kk[((size_t)bl * NN + i) * MM + j] = pack_key64(v, j);
      }
    }
  }
}

// ------- top-20 per row from exact u64 keys; no fallback -------
__global__ __launch_bounds__(256) void k_topk(const u64* __restrict__ kk,
                                              int* __restrict__ idx, int b0) {
  int wave = threadIdx.x >> 6;
  int lane = threadIdx.x & 63;
  int bl = blockIdx.x;
  int row = blockIdx.y * 4 + wave;
  const u64* rp = kk + ((size_t)bl * NN + row) * MM;
  u64 s[16];
#pragma unroll
  for (int m = 0; m < 16; ++m) s[m] = rp[m * 64 + lane];
  int* op = idx + ((size_t)(b0 + bl) * NN + row) * KNN;
  topk20_u64(s, lane, op);
}

// --- fused per-point feature matmul (f64), both modes in one launch ---
// mode 0: out0[b,j,o] = sum_c src0[b,j,c]*w[o,c]
// mode 1: out1[b,j,o] = sum_c src1[b,j,c]*(w[o,C+c]-w[o,c])
// MFMA path (if *flag) with probe-decoded D tables; VALU fallback otherwise.
__global__ __launch_bounds__(256) void k_featmm2(
    const double* __restrict__ src0, int ld0, int Np0,
    const double* __restrict__ src1, int ld1,
    const float* __restrict__ w, int CW,
    double* __restrict__ out0, double* __restrict__ out1, int C, int O,
    const int* __restrict__ rowt, const int* __restrict__ colt,
    const int* __restrict__ flag) {
  __shared__ double As[16][68];
  __shared__ double Ws[16][68];
  int nbo = O >> 6;
  int b = blockIdx.x;
  int mode = blockIdx.y >= nbo;
  int o0 = (blockIdx.y - (mode ? nbo : 0)) * 64;
  int j0 = blockIdx.z * 64;
  const double* src = mode ? src1 : src0;
  int lds_ = mode ? ld1 : ld0;
  int Np = mode ? NN : Np0;
  double* out = mode ? out1 : out0;
  int tid = threadIdx.x;
  const double* Sb = src + (size_t)b * Np * lds_;
  if (*flag) {
    int lane = tid & 63, wv = tid >> 6;
    int lm = lane & 15, lq = lane >> 4;
    f64x4 acc[4] = {};
    for (int c0 = 0; c0 < C; c0 += 16) {
      if (c0) __syncthreads();
      for (int r = 0; r < 4; ++r) {
        int li = tid + r * 256;
        int row = li >> 4, k = li & 15;
        int c = c0 + k;
        As[k][row] = (c < C) ? Sb[(size_t)(j0 + row) * lds_ + c] : 0.0;
        double wvv = 0.0;
        if (c < C) {
          const float* wr = w + (size_t)(o0 + row) * CW;
          wvv = (mode == 0) ? (double)wr[c] : ((double)wr[C + c] - (double)wr[c]);
        }
        Ws[k][row] = wvv;
      }
      __syncthreads();
#pragma unroll
      for (int kc = 0; kc < 4; ++kc) {
        double a = As[kc * 4 + lq][wv * 16 + lm];
#pragma unroll
        for (int t = 0; t < 4; ++t) {
          double bb = Ws[kc * 4 + lq][t * 16 + lm];
          acc[t] = __builtin_amdgcn_mfma_f64_16x16x4f64(a, bb, acc[t], 0, 0, 0);
        }
      }
    }
    int rta[4], cta[4];
#pragma unroll
    for (int r = 0; r < 4; ++r) {
      rta[r] = rowt[lane * 4 + r];
      cta[r] = colt[lane * 4 + r];
    }
#pragma unroll
    for (int t = 0; t < 4; ++t) {
#pragma unroll
      for (int r = 0; r < 4; ++r) {
        int j = j0 + wv * 16 + rta[r];
        int o = o0 + t * 16 + cta[r];
        out[((size_t)b * Np + j) * O + o] = acc[t][r];
      }
    }
  } else {
    int tx = tid & 15, ty = tid >> 4;
    double acc[4][4] = {};
    for (int c0 = 0; c0 < C; c0 += 16) {
      if (c0) __syncthreads();
      for (int r = 0; r < 4; ++r) {
        int li = tid + r * 256;
        int row = li >> 4, k = li & 15;
        int c = c0 + k;
        As[k][row] = (c < C) ? Sb[(size_t)(j0 + row) * lds_ + c] : 0.0;
        double wvv = 0.0;
        if (c < C) {
          const float* wr = w + (size_t)(o0 + row) * CW;
          wvv = (mode == 0) ? (double)wr[c] : ((double)wr[C + c] - (double)wr[c]);
        }
        Ws[k][row] = wvv;
      }
      __syncthreads();
#pragma unroll
      for (int k = 0; k < 16; ++k) {
        double a_[4], b_[4];
#pragma unroll
        for (int ii = 0; ii < 4; ++ii) a_[ii] = As[k][ty * 4 + ii];
#pragma unroll
        for (int jj = 0; jj < 4; ++jj) b_[jj] = Ws[k][tx * 4 + jj];
#pragma unroll
        for (int ii = 0; ii < 4; ++ii)
#pragma unroll
          for (int jj = 0; jj < 4; ++jj)
            acc[ii][jj] = fma(a_[ii], b_[jj], acc[ii][jj]);
      }
    }
    for (int ii = 0; ii < 4; ++ii) {
      int j = j0 + ty * 4 + ii;
      double* op = &out[((size_t)b * Np + j) * O + o0 + tx * 4];
      double2 v0, v1;
      v0.x = acc[ii][0];
      v0.y = acc[ii][1];
      v1.x = acc[ii][2];
      v1.y = acc[ii][3];
      *(double2*)op = v0;
      *(double2*)(op + 2) = v1;
    }
  }
}

// ---- layer-5 GEMM via bf16 MFMA: per-wave 16x16 tile, frags direct from global ----
__global__ __launch_bounds__(256) void k_gemm5_mfma(
    const __hip_bfloat16* __restrict__ cath, const __hip_bfloat16* __restrict__ w5h,
    float* __restrict__ out) {
  int b = blockIdx.x;
  int j0 = blockIdx.y * 16;
  int o0 = blockIdx.z * 64 + (threadIdx.x >> 6) * 16;
  int lane = threadIdx.x & 63;
  int m = lane & 15;
  int quad = lane >> 4;
  const __hip_bfloat16* arow = cath + ((size_t)b * NN + j0 + m) * 512 + quad * 8;
  const __hip_bfloat16* brow = w5h + (size_t)(o0 + m) * 512 + quad * 8;
  f32x4 acc = {0.f, 0.f, 0.f, 0.f};
#pragma unroll
  for (int c0 = 0; c0 < 512; c0 += 32) {
    bf16x8 a = *(const bf16x8*)(arow + c0);
    bf16x8 bb = *(const bf16x8*)(brow + c0);
    acc = __builtin_amdgcn_mfma_f32_16x16x32_bf16(a, bb, acc, 0, 0, 0);
  }
  float* obase = &out[((size_t)b * NN + j0 + quad * 4) * 512 + o0 + m];
#pragma unroll
  for (int r = 0; r < 4; ++r) obase[(size_t)r * 512] = acc[r];
}

// ------- fused gather (f64): per (n,o) max_k y, accumulate BN stats -------
__global__ __launch_bounds__(256) void k_gather(
    const double* __restrict__ u, const double* __restrict__ t, const int* __restrict__ idx,
    double* __restrict__ stats, double* __restrict__ mx, int O, int srcNp) {
  __shared__ int lidx[16 * KNN];
  __shared__ double rs[256];
  __shared__ double rq[256];
  int b = blockIdx.x;
  int n0 = blockIdx.y * 16;
  int o0 = blockIdx.z * 64;
  int tid = threadIdx.x;
  int lane = tid & 63, nsl = tid >> 6;
  for (int w = tid; w < 16 * KNN; w += 256)
    lidx[w] = idx[((size_t)b * NN + n0) * KNN + w];
  __syncthreads();
  int oo = o0 + lane;
  double s1 = 0.0, s2 = 0.0;
  for (int ns = nsl; ns < 16; ns += 4) {
    size_t row = (size_t)b * NN + n0 + ns;
    double tv = t[row * O + oo];
    double mxv = -INFINITY;
    double a1 = 0.0, a2 = 0.0;
#pragma unroll
    for (int k = 0; k < KNN; ++k) {
      int j = lidx[ns * KNN + k];
      double yv = u[((size_t)b * srcNp + j) * O + oo] + tv;
      mxv = fmax(mxv, yv);
      a1 += yv;
      a2 = fma(yv, yv, a2);
    }
    mx[row * O + oo] = mxv;
    s1 += a1;
    s2 += a2;
  }
  rs[tid] = s1;
  rq[tid] = s2;
  __syncthreads();
  if (tid < 64) {
    s1 = rs[tid] + rs[tid + 64] + rs[tid + 128] + rs[tid + 192];
    s2 = rq[tid] + rq[tid + 64] + rq[tid + 128] + rq[tid + 192];
    atomicAdd(&stats[o0 + tid], s1);
    atomicAdd(&stats[O + o0 + tid], s2);
  }
}

// ---------------- fold BN into per-channel scale/shift (f64) ----------------
__global__ void k_bnfin(const double* __restrict__ stats, const float* __restrict__ gamma,
                        const float* __restrict__ beta, double* __restrict__ sc,
                        int O, double cnt) {
  int o = threadIdx.x;
  if (o >= O) return;
  double mean = stats[o] / cnt;
  double var = stats[O + o] / cnt - mean * mean;
  if (var < 0.0) var = 0.0;
  double rstd = 1.0 / sqrt(var + 1e-5);
  double s = (double)gamma[o] * rstd;
  double c = (double)beta[o] - mean * s;
  sc[o] = s;
  sc[O + o] = c;
}

// --- apply BN+lrelu to stored max (f64); write catd (f64, knn channels) + bf16 ---
__global__ __launch_bounds__(256) void k_bnapply(
    const double* __restrict__ mx, const double* __restrict__ u, const double* __restrict__ t,
    const int* __restrict__ idx, const double* __restrict__ sc, double* __restrict__ catd,
    __hip_bfloat16* __restrict__ cath, int coff, int O, int srcNp) {
  int i = blockIdx.x * 256 + threadIdx.x;
  int total = BB * NN * O;
  if (i >= total) return;
  int oo = i % O;
  int n = (i / O) % NN;
  int b = i / (O * NN);
  double s = sc[oo], c = sc[O + oo];
  double v;
  if (s >= 0.0) {
    v = mx[i];
  } else {  // monotone-decreasing transform needs min_k y (never hit with gamma=1)
    double tv = t[i];
    double mn = INFINITY;
    for (int k = 0; k < KNN; ++k) {
      int j = idx[((size_t)b * NN + n) * KNN + k];
      mn = fmin(mn, u[((size_t)b * srcNp + j) * O + oo] + tv);
    }
    v = mn;
  }
  double a = s * v + c;
  a = (a >= 0.0) ? a : 0.2 * a;
  size_t ci = ((size_t)b * NN + n) * 512 + coff + oo;
  cath[ci] = __float2bfloat16((float)a);
  if (coff < 256) catd[((size_t)b * NN + n) * 256 + coff + oo] = a;
}

// ------- layer 5 streaming stats over stored y5 (B,N,512) -------
__global__ __launch_bounds__(256) void k_stats512(
    const float* __restrict__ y5, double* __restrict__ stats) {
  int b = blockIdx.y;
  int n0 = blockIdx.x * 32;
  int tid = threadIdx.x;
  for (int part = 0; part < 2; ++part) {
    int oo = tid + part * 256;
    float a1 = 0.f, a2 = 0.f;
    for (int ns = 0; ns < 32; ++ns) {
      float v = y5[((size_t)b * NN + n0 + ns) * 512 + oo];
      a1 += v;
      a2 = fmaf(v, v, a2);
    }
    atomicAdd(&stats[oo], (double)a1);
    atomicAdd(&stats[512 + oo], (double)a2);
  }
}

// ------- layer 5 finalize: BN+lrelu on stored y5, transpose, f32 store -------
__global__ __launch_bounds__(256) void k_final5b(
    const float* __restrict__ y5, const double* __restrict__ sc, float* __restrict__ out) {
  __shared__ float tile[64][65];
  int b = blockIdx.z;
  int n0 = blockIdx.x * 64;
  int o0 = blockIdx.y * 64;
  int tid = threadIdx.x;
  for (int r = 0; r < 16; ++r) {
    int li = tid + r * 256;
    int nl = li >> 6, ol = li & 63;
    float v = y5[((size_t)b * NN + n0 + nl) * 512 + o0 + ol];
    float a = (float)(sc[o0 + ol] * (double)v + sc[512 + o0 + ol]);
    a = (a >= 0.f) ? a : NEG_SLOPE * a;
    tile[nl][ol] = a;
  }
  __syncthreads();
  for (int r = 0; r < 16; ++r) {
    int li = tid + r * 256;
    int ol = li >> 6, nl = li & 63;
    out[((size_t)b * 512 + o0 + ol) * NN + n0 + nl] = tile[nl][ol];
  }
}

// =====================================================================================
// r19: probe validated (r18 gram MfmaUtil 38.5% proves MFMA path engaged) but gram sat
// at 2.45x off the 78.6 TF f64-MFMA roofline -- single-buffered stage->barrier->compute
// stalls every K-block + low per-wave MFMA density. Fix: (1) gram 128x64 tile,
// double-buffered reg-staged (issue next block's global loads BEFORE compute, ds_write
// after, ONE barrier/block), 32 MFMA/wave/block; (2) featmm2 moved to the same f64-MFMA
// path (was 31-TF VALU, ~35us at L4). Both keep probe-gated VALU fallbacks.
extern "C" void kernel_launch(void* const* d_in, const int* in_sizes, int n_in,
                              void* d_out, int out_size, void* d_ws, size_t ws_size,
                              hipStream_t stream) {
  const float* x = (const float*)d_in[0];
  const float* y = (const float*)d_in[1];
  const float* w1 = (const float*)d_in[2];
  const float* w2 = (const float*)d_in[3];
  const float* w3 = (const float*)d_in[4];
  const float* w4 = (const float*)d_in[5];
  const float* w5 = (const float*)d_in[6];
  const float* g1 = (const float*)d_in[7];
  const float* b1 = (const float*)d_in[8];
  const float* g2 = (const float*)d_in[9];
  const float* b2 = (const float*)d_in[10];
  const float* g3 = (const float*)d_in[11];
  const float* b3 = (const float*)d_in[12];
  const float* g4 = (const float*)d_in[13];
  const float* b4 = (const float*)d_in[14];
  const float* g5 = (const float*)d_in[15];
  const float* b5 = (const float*)d_in[16];

  char* base = (char*)d_ws;
  size_t off = 0;
  auto alloc = [&](size_t bytes) -> char* {
    char* p = base + off;
    off += (bytes + 255) & ~(size_t)255;
    return p;
  };
  double* st = (double*)alloc(1024 * 8);
  double* sc = (double*)alloc(1024 * 8);
  double* sq = (double*)alloc((size_t)BB * NN * 8);
  double* rnx = (double*)alloc((size_t)BB * NN * 8);
  double* rny = (double*)alloc((size_t)BB * MM * 8);
  int* idxb = (int*)alloc((size_t)BB * NN * KNN * 4);
  int* rowt = (int*)alloc(256 * 4);
  int* colt = (int*)alloc(256 * 4);
  int* pflag = (int*)alloc(256);
  double* xs3d = (double*)alloc((size_t)BB * NN * 3 * 8);
  double* ysd = (double*)alloc((size_t)BB * MM * 128 * 8);
  double* catd = (double*)alloc((size_t)BB * NN * 256 * 8);  // knn channels 0..255
  __hip_bfloat16* cath = (__hip_bfloat16*)alloc((size_t)BB * NN * 512 * 2);
  __hip_bfloat16* w5h = (__hip_bfloat16*)alloc((size_t)512 * 512 * 2);
  double* uu = (double*)alloc((size_t)BB * MM * 256 * 8);  // src term (max O=256)
  double* tt = (double*)alloc((size_t)BB * NN * 256 * 8);  // center term
  size_t kkBatchBytes = (size_t)NN * MM * 8;  // 8 MB per batch (u64 keys)
  size_t avail = (ws_size > off) ? (ws_size - off) : 0;
  int CB = (int)(avail / kkBatchBytes);
  if (CB < 1) CB = 1;
  if (CB > BB) CB = BB;
  u64* KK = (u64*)alloc((size_t)CB * kkBatchBytes);
  float* y5 = (float*)uu;             // layer-5 pre-BN (16MB), uu dead by then
  double* mx = (double*)d_out;        // max_k y (f64, <=16MB == out_size)
  float* outp = (float*)d_out;

  const double cntE = (double)BB * NN * KNN;

  auto knn = [&](const double* A, int lda, const double* Bm, int ldb,
                 const double* sa, const double* sb, int C, int mode) {
    for (int b0 = 0; b0 < BB; b0 += CB) {
      int cb = (BB - b0 < CB) ? (BB - b0) : CB;
      dim3 g(cb, MM / 64, NN / 128);
      if (mode == 1)
        k_gram_u<1><<<g, 256, 0, stream>>>(A, lda, Bm, ldb, sa, sb, KK, C, b0, rowt,
                                           colt, pflag);
      else
        k_gram_u<2><<<g, 256, 0, stream>>>(A, lda, Bm, ldb, sa, sb, KK, C, b0, rowt,
                                           colt, pflag);
      k_topk<<<dim3(cb, 256), 256, 0, stream>>>(KK, idxb, b0);
    }
  };

  auto edge_layer = [&](const double* ctr, int ldc, const double* src, int ldsrc,
                        int srcNp, const float* w, int CW, const float* g,
                        const float* bb, int C, int O, int coff) {
    k_featmm2<<<dim3(8, 2 * (O / 64), 16), 256, 0, stream>>>(
        src, ldsrc, srcNp, ctr, ldc, w, CW, uu, tt, C, O, rowt, colt, pflag);
    hipMemsetAsync(st, 0, 1024 * 8, stream);
    k_gather<<<dim3(BB, NN / 16, O / 64), 256, 0, stream>>>(uu, tt, idxb, st, mx, O,
                                                            srcNp);
    k_bnfin<<<1, O, 0, stream>>>(st, g, bb, sc, O, cntE);
    k_bnapply<<<(BB * NN * O + 255) / 256, 256, 0, stream>>>(mx, uu, tt, idxb, sc, catd,
                                                             cath, coff, O, srcNp);
  };

  // ---- f64-MFMA layout probe (fused decode) + input transposes + w5 bf16 ----
  k_probe_mfma<<<1, 64, 0, stream>>>(rowt, colt, pflag);
  k_transpose_d<<<96, 256, 0, stream>>>(x, xs3d, 3, NN);
  k_transpose_d<<<2048, 256, 0, stream>>>(y, ysd, 128, MM);
  k_cvt_bf16<<<1024, 256, 0, stream>>>(w5, w5h, 512 * 512);

  // ---- layer 1: C=3, O=64 (fused knn, no gram) ----
  k_rowsq<0><<<32, 256, 0, stream>>>(xs3d, 3, 3, sq);
  k_knn3<<<dim3(BB, 256), 256, 0, stream>>>(xs3d, sq, idxb);
  edge_layer(xs3d, 3, xs3d, 3, NN, w1, 6, g1, b1, 3, 64, 0);

  // ---- layer 2: x1 = catd[:,0:64], C=64, O=64 ----
  k_rowsq<0><<<32, 256, 0, stream>>>(catd, 256, 64, sq);
  knn(catd, 256, catd, 256, sq, sq, 64, 1);
  edge_layer(catd, 256, catd, 256, NN, w2, 128, g2, b2, 64, 64, 64);

  // ---- layer 3: x2 = catd[:,64:128], C=64, O=128 ----
  k_rowsq<0><<<32, 256, 0, stream>>>(catd + 64, 256, 64, sq);
  knn(catd + 64, 256, catd + 64, 256, sq, sq, 64, 1);
  edge_layer(catd + 64, 256, catd + 64, 256, NN, w3, 128, g3, b3, 64, 128, 128);

  // ---- layer 4 (IA): x3 = catd[:,128:256], src = y (cosine knn), C=128, O=256 ----
  k_rowsq<1><<<32, 256, 0, stream>>>(catd + 128, 256, 128, rnx);
  k_rowsq<1><<<32, 256, 0, stream>>>(ysd, 128, 128, rny);
  knn(catd + 128, 256, ysd, 128, rnx, rny, 128, 2);
  edge_layer(catd + 128, 256, ysd, 128, MM, w4, 256, g4, b4, 128, 256, 256);

  // ---- layer 5: bf16-MFMA GEMM -> y5 (aliases uu), BN over (B,N), lrelu, transpose ----
  hipMemsetAsync(st, 0, 1024 * 8, stream);
  k_gemm5_mfma<<<dim3(BB, 64, 8), 256, 0, stream>>>(cath, w5h, y5);
  k_stats512<<<dim3(32, 8), 256, 0, stream>>>(y5, st);
  k_bnfin<<<1, 512, 0, stream>>>(st, g5, b5, sc, 512, (double)(BB * NN));
  k_final5b<<<dim3(16, 8, 8), 256, 0, stream>>>(y5, sc, outp);
}